// Round 4
// baseline (2770.797 us; speedup 1.0000x reference)
//
#include <hip/hip_runtime.h>
#include <hip/hip_bf16.h>

// ---------------------------------------------------------------------------
// RNN_17214228922840: GraphRNN-ish model. fp32 I/O, bf16 MFMA compute.
//   B=128, TV=32, TE=64, VOCAB=1024, EMB=256, H=512 (3H=1536), REPR=128, NET=8
// Outputs (flat, fp32): O_vertex [128,1024,32] | O_edge [128,32,2,64] | O_edge_type [128,8,64]
// Row spaces are b-major: row = b*T + t.
// gi layout (C-frag-major): [t][grp(8)][gate(3)][col(512)][row16]
// ---------------------------------------------------------------------------

typedef __bf16 bf16_t;
typedef bf16_t bf16x8 __attribute__((ext_vector_type(8)));
typedef bf16_t bf16x4 __attribute__((ext_vector_type(4)));
typedef float  f32x4  __attribute__((ext_vector_type(4)));

// workspace layout (bf16 element offsets)
#define OFF_GIV  0ull                    // 32*8*3*512*16 = 6291456
#define OFF_GIE  6291456ull              // 64*8*3*512*16 = 12582912
#define OFF_HV   18874368ull             // 128*32*512 (b-major)
#define OFF_HE   20971520ull             // 128*64*512 (b-major)
#define OFF_VREP 25165824ull             // 128*32*128 (b-major)
#define OFF_EREP 25690112ull             // 128*64*128 (b-major)
#define OFF_CVT  27002880ull             // converted bf16 weights below
#define CVT_VEMB  0ull
#define CVT_EEMB  262144ull
#define CVT_VWI   270336ull
#define CVT_EWI   663552ull
#define CVT_VWH   1449984ull
#define CVT_EWH   2236416ull
#define CVT_VOUT  3022848ull
#define CVT_VREPW 3547136ull
#define CVT_EREPW 3612672ull

// output flat offsets (fp32 elements)
#define OUT_OV 0ull
#define OUT_OE 4194304ull
#define OUT_OT 4718592ull

__device__ __forceinline__ float fsigmoid(float x) {
    float e = __builtin_amdgcn_exp2f(-x * 1.4426950408889634f);
    return __builtin_amdgcn_rcpf(1.0f + e);
}
__device__ __forceinline__ float ftanh(float x) {
    x = fminf(x, 15.0f);
    float e = __builtin_amdgcn_exp2f(x * 2.8853900817779268f); // exp(2x)
    return (e - 1.0f) * __builtin_amdgcn_rcpf(e + 1.0f);
}

// ---------------------------------------------------------------------------
// prep: fp32 -> bf16 downcast of weights/embeddings (3592 blocks x 1024 elem)
// ---------------------------------------------------------------------------
__global__ __launch_bounds__(256) void prep_kernel(
    const float* __restrict__ vemb, const float* __restrict__ eemb,
    const float* __restrict__ vwi,  const float* __restrict__ ewi,
    const float* __restrict__ vwh,  const float* __restrict__ ewh,
    const float* __restrict__ voutw, const float* __restrict__ vrepw,
    const float* __restrict__ erepw, bf16_t* __restrict__ cvt)
{
    int blk = blockIdx.x;
    const float* src; bf16_t* dst; int lb;
    if (blk < 256)       { src = vemb;  dst = cvt + CVT_VEMB;  lb = blk; }
    else if (blk < 264)  { src = eemb;  dst = cvt + CVT_EEMB;  lb = blk - 256; }
    else if (blk < 648)  { src = vwi;   dst = cvt + CVT_VWI;   lb = blk - 264; }
    else if (blk < 1416) { src = ewi;   dst = cvt + CVT_EWI;   lb = blk - 648; }
    else if (blk < 2184) { src = vwh;   dst = cvt + CVT_VWH;   lb = blk - 1416; }
    else if (blk < 2952) { src = ewh;   dst = cvt + CVT_EWH;   lb = blk - 2184; }
    else if (blk < 3464) { src = voutw; dst = cvt + CVT_VOUT;  lb = blk - 2952; }
    else if (blk < 3528) { src = vrepw; dst = cvt + CVT_VREPW; lb = blk - 3464; }
    else                 { src = erepw; dst = cvt + CVT_EREPW; lb = blk - 3528; }
    int idx = lb * 1024 + threadIdx.x * 4;
    float4 v = *(const float4*)(src + idx);
    bf16x4 o;
    o[0] = (bf16_t)v.x; o[1] = (bf16_t)v.y; o[2] = (bf16_t)v.z; o[3] = (bf16_t)v.w;
    *(bf16x4*)(dst + idx) = o;
}

// ---------------------------------------------------------------------------
// Generic C = gather(A) @ W^T + bias GEMM. Wave computes 64x64 (4x4 MFMA tiles).
// Rows are b-major: row = b*TT + t.
// GATHER: 0 dense A[M,K]; 1 vertex emb gather (K=256); 2 edge emb pair (K=512)
// OUTMODE: 0 row-major C[row*N+col]
//          1 O_vertex: float4 at [(b*1024+col)*32 + t] (TT=32, CT=float)
//          2 gi scatter: [((t*8+grp)*3+gate)*512+col]*16 + r   (b=grp*16+r)
// ---------------------------------------------------------------------------
template<int GATHER, int OUTMODE, int K, int TT, typename CT>
__global__ __launch_bounds__(256) void gemm_bt(
    const bf16_t* __restrict__ A, const bf16_t* __restrict__ W,
    const float* __restrict__ bias, CT* __restrict__ C,
    const int* __restrict__ gidx, const bf16_t* __restrict__ emb, int N)
{
    constexpr int K32 = K / 32;
    const int tid = threadIdx.x, lane = tid & 63, wv = tid >> 6;
    const int r16 = lane & 15, quad = lane >> 4, koff = quad * 8;
    const int mbase = blockIdx.x * 256 + wv * 64;
    const int nbase = blockIdx.y * 64;

    const bf16_t* ap0[4];
    const bf16_t* ap1[4];
#pragma unroll
    for (int i = 0; i < 4; ++i) {
        int row = mbase + i * 16 + r16;
        if (GATHER == 0) {
            ap0[i] = A + (size_t)row * K + koff;
            ap1[i] = ap0[i];
        } else if (GATHER == 1) {
            int idx = gidx[row];                    // row = b*32+t, gidx[b][32]
            ap0[i] = emb + (size_t)idx * 256 + koff;
            ap1[i] = ap0[i];
        } else {
            int c = row * 3;                        // row = b*64+t, input_edge[b][64][3]
            ap0[i] = emb + (size_t)gidx[c] * 256 + koff;
            ap1[i] = emb + (size_t)gidx[c + 1] * 256 + koff;
        }
    }
    const bf16_t* bp[4];
#pragma unroll
    for (int j = 0; j < 4; ++j)
        bp[j] = W + (size_t)(nbase + j * 16 + r16) * K + koff;

    f32x4 acc[4][4];
#pragma unroll
    for (int i = 0; i < 4; ++i)
#pragma unroll
        for (int j = 0; j < 4; ++j) acc[i][j] = (f32x4){0.f, 0.f, 0.f, 0.f};

    for (int kc = 0; kc < K32; ++kc) {
        bf16x8 a[4], b[4];
#pragma unroll
        for (int i = 0; i < 4; ++i) {
            const bf16_t* p;
            if (GATHER == 2) p = (kc < 8) ? (ap0[i] + kc * 32) : (ap1[i] + (kc - 8) * 32);
            else             p = ap0[i] + kc * 32;
            a[i] = *(const bf16x8*)p;
        }
#pragma unroll
        for (int j = 0; j < 4; ++j) b[j] = *(const bf16x8*)(bp[j] + kc * 32);
#pragma unroll
        for (int i = 0; i < 4; ++i)
#pragma unroll
            for (int j = 0; j < 4; ++j)
                acc[i][j] = __builtin_amdgcn_mfma_f32_16x16x32_bf16(a[i], b[j], acc[i][j], 0, 0, 0);
    }

#pragma unroll
    for (int j = 0; j < 4; ++j) {
        int col = nbase + j * 16 + r16;
        float bf = bias[col];
        int gate = col >> 9, cw = col & 511;        // OUTMODE 2 decomposition
#pragma unroll
        for (int i = 0; i < 4; ++i) {
            if (OUTMODE == 1) {
                int rowq = mbase + i * 16 + quad * 4;   // 4 consecutive t in one b
                int b = rowq >> 5, t0 = rowq & 31;
                float4 v4;
                v4.x = acc[i][j][0] + bf; v4.y = acc[i][j][1] + bf;
                v4.z = acc[i][j][2] + bf; v4.w = acc[i][j][3] + bf;
                *(float4*)((float*)C + ((size_t)(b * 1024) + col) * 32 + t0) = v4;
            } else {
#pragma unroll
                for (int q = 0; q < 4; ++q) {
                    int row = mbase + i * 16 + quad * 4 + q;
                    float v = acc[i][j][q] + bf;
                    if (OUTMODE == 0) {
                        C[(size_t)row * N + col] = (CT)v;
                    } else {            // OUTMODE == 2: gi scatter
                        int b = row / TT, t = row % TT;
                        int grp = b >> 4, r = b & 15;
                        C[(size_t)((((t * 8 + grp) * 3 + gate) * 512 + cw) * 16 + r)] = (CT)v;
                    }
                }
            }
        }
    }
}

// ---------------------------------------------------------------------------
// Fused GRU scans, single block per group (NO inter-block sync).
// Blocks 0..7 vertex groups (T=32), 8..15 edge groups (T=64). 1024 thr = 16
// waves; wave owns 32 h-cols (2 strips x 3 gates -> wfrag 384 VGPR; LB(1024,4)
// = 512-reg cap = full RF). h double-buffered in LDS; one barrier per step.
// ---------------------------------------------------------------------------
__global__ __launch_bounds__(1024, 4) void gru_scan(
    const bf16_t* __restrict__ giV, const bf16_t* __restrict__ giE,
    const bf16_t* __restrict__ WhV, const bf16_t* __restrict__ WhE,
    const float* __restrict__ bhV, const float* __restrict__ bhE,
    bf16_t* __restrict__ hV, bf16_t* __restrict__ hE)
{
    const int blk  = blockIdx.x;
    const int role = blk >> 3;          // 0 vertex, 1 edge
    const int grp  = blk & 7;
    const bf16_t* gi = role ? giE : giV;
    const bf16_t* Wh = role ? WhE : WhV;
    const float*  bh = role ? bhE : bhV;
    bf16_t* hout = role ? hE : hV;
    const int T = role ? 64 : 32;
    const int bb = grp * 16;

    const int tid = threadIdx.x, lane = tid & 63, wv = tid >> 6;
    const int r16 = lane & 15, quad = lane >> 4, koff = quad * 8;
    const int jA = wv * 32 + r16;       // strip A col; strip B = jA + 16

    // --- Wh slice in registers: wfrag[strip][gate][kc] = 384 VGPRs ---
    bf16x8 wfrag[2][3][16];
#pragma unroll
    for (int s2 = 0; s2 < 2; ++s2)
#pragma unroll
        for (int g = 0; g < 3; ++g) {
            const bf16_t* wrow = Wh + ((size_t)(g * 512 + jA + s2 * 16)) * 512 + koff;
#pragma unroll
            for (int kc = 0; kc < 16; ++kc)
                wfrag[s2][g][kc] = *(const bf16x8*)(wrow + kc * 32);
        }
    float bhv[2][3];
#pragma unroll
    for (int s2 = 0; s2 < 2; ++s2)
#pragma unroll
        for (int g = 0; g < 3; ++g) bhv[s2][g] = bh[g * 512 + jA + s2 * 16];

    float hq[2][4] = {{0.f,0.f,0.f,0.f},{0.f,0.f,0.f,0.f}};

    __shared__ __align__(16) bf16_t hbf0[16][520];
    __shared__ __align__(16) bf16_t hbf1[16][520];
    for (int i = tid; i < 16 * 512; i += 1024)
        hbf0[i >> 9][i & 511] = (bf16_t)0.f;
    __syncthreads();

    for (int t = 0; t < T; ++t) {
        // gi prefetch: 6 x 8B loads (C-frag-major layout)
        bf16x4 gp[2][3];
        int gib = ((t * 8 + grp) * 3) * 8192;       // *512*16
#pragma unroll
        for (int s2 = 0; s2 < 2; ++s2)
#pragma unroll
            for (int g = 0; g < 3; ++g)
                gp[s2][g] = *(const bf16x4*)(gi + gib + (g * 512 + jA + s2 * 16) * 16 + quad * 4);

        // MFMA: gh for this wave's 2 strips x 3 gates
        const bf16_t (*cur)[520] = (t & 1) ? hbf1 : hbf0;
        f32x4 acc[2][3];
#pragma unroll
        for (int s2 = 0; s2 < 2; ++s2)
#pragma unroll
            for (int g = 0; g < 3; ++g) acc[s2][g] = (f32x4){0.f,0.f,0.f,0.f};
#pragma unroll
        for (int kc = 0; kc < 16; ++kc) {
            bf16x8 a = *(const bf16x8*)&cur[r16][kc * 32 + koff];
#pragma unroll
            for (int s2 = 0; s2 < 2; ++s2)
#pragma unroll
                for (int g = 0; g < 3; ++g)
                    acc[s2][g] = __builtin_amdgcn_mfma_f32_16x16x32_bf16(a, wfrag[s2][g][kc], acc[s2][g], 0, 0, 0);
        }

        // gates + h update (C-frag: col=r16-strip, row=quad*4+q)
        bf16_t (*nxt)[520] = (t & 1) ? hbf0 : hbf1;
#pragma unroll
        for (int s2 = 0; s2 < 2; ++s2) {
            int j = jA + s2 * 16;
#pragma unroll
            for (int q = 0; q < 4; ++q) {
                int br = quad * 4 + q;
                float ir = (float)gp[s2][0][q];
                float iz = (float)gp[s2][1][q];
                float inn = (float)gp[s2][2][q];
                float r = fsigmoid(ir + acc[s2][0][q] + bhv[s2][0]);
                float z = fsigmoid(iz + acc[s2][1][q] + bhv[s2][1]);
                float n = ftanh(inn + r * (acc[s2][2][q] + bhv[s2][2]));
                float hnew = (1.0f - z) * n + z * hq[s2][q];
                hq[s2][q] = hnew;
                bf16_t hb = (bf16_t)hnew;
                nxt[br][j] = hb;
                hout[((size_t)((bb + br) * T + t)) * 512 + j] = hb;  // b-major
            }
        }
        __syncthreads();
    }
}

// O_edge_type[b,k,te] = erep[b,te,:] . etype_W[k,:] + etype_b[k]
__global__ __launch_bounds__(256) void etype_kernel(
    const bf16_t* __restrict__ erep, const float* __restrict__ W,
    const float* __restrict__ bias, float* __restrict__ out)
{
    int o = blockIdx.x * 256 + threadIdx.x;      // 65536 outputs
    int te = o & 63, k = (o >> 6) & 7, b = o >> 9;
    float sacc = bias[k];
    const bf16_t* e = erep + ((size_t)(b * 64 + te)) * 128;
    const float* w = W + k * 128;
#pragma unroll 8
    for (int r = 0; r < 128; ++r) sacc += (float)e[r] * w[r];
    out[OUT_OT + o] = sacc;
}

// O_edge[b,tv,{0,1},te] = sum_r tanh(e[b,te,r]+v[b,tv,r]) * {src,dst}_w[r] + b
__global__ __launch_bounds__(256) void attn_kernel(
    const bf16_t* __restrict__ erep, const bf16_t* __restrict__ vrep,
    const float* __restrict__ src_w, const float* __restrict__ src_b,
    const float* __restrict__ dst_w, const float* __restrict__ dst_b,
    float* __restrict__ out)
{
    int b = blockIdx.x >> 1, half = blockIdx.x & 1;
    __shared__ float es[32][129], vs[32][129], swf[128], dwf[128];
    int tid = threadIdx.x;
    for (int f = tid; f < 32 * 128; f += 256) {
        int i = f >> 7, r = f & 127;
        es[i][r] = (float)erep[((size_t)(b * 64 + half * 32 + i)) * 128 + r];
        vs[i][r] = (float)vrep[((size_t)(b * 32 + i)) * 128 + r];
    }
    if (tid < 128) { swf[tid] = src_w[tid]; dwf[tid] = dst_w[tid]; }
    __syncthreads();
    float sb = src_b[0], db = dst_b[0];
    for (int p = tid; p < 1024; p += 256) {
        int te = p & 31, tv = p >> 5;
        float sacc = 0.f, dacc = 0.f;
#pragma unroll 4
        for (int r = 0; r < 128; ++r) {
            float u = ftanh(es[te][r] + vs[tv][r]);
            sacc += u * swf[r];
            dacc += u * dwf[r];
        }
        int teg = half * 32 + te;
        size_t base = OUT_OE + ((size_t)(b * 32 + tv) * 2) * 64;
        out[base + teg]      = sacc + sb;
        out[base + 64 + teg] = dacc + db;
    }
}

extern "C" void kernel_launch(void* const* d_in, const int* in_sizes, int n_in,
                              void* d_out, int out_size, void* d_ws, size_t ws_size,
                              hipStream_t stream)
{
    const int*   input_vertex = (const int*)d_in[0];
    const int*   input_edge   = (const int*)d_in[1];
    const float* vertex_emb   = (const float*)d_in[2];
    const float* v_Wi  = (const float*)d_in[3];
    const float* v_Wh  = (const float*)d_in[4];
    const float* v_bi  = (const float*)d_in[5];
    const float* v_bh  = (const float*)d_in[6];
    const float* vout_W = (const float*)d_in[7];
    const float* vout_b = (const float*)d_in[8];
    const float* vrep_W = (const float*)d_in[9];
    const float* vrep_b = (const float*)d_in[10];
    const float* edge_emb = (const float*)d_in[11];
    const float* e_Wi  = (const float*)d_in[12];
    const float* e_Wh  = (const float*)d_in[13];
    const float* e_bi  = (const float*)d_in[14];
    const float* e_bh  = (const float*)d_in[15];
    const float* erep_W = (const float*)d_in[16];
    const float* erep_b = (const float*)d_in[17];
    const float* etype_W = (const float*)d_in[18];
    const float* etype_b = (const float*)d_in[19];
    const float* src_w = (const float*)d_in[20];
    const float* src_b = (const float*)d_in[21];
    const float* dst_w = (const float*)d_in[22];
    const float* dst_b = (const float*)d_in[23];

    bf16_t* ws   = (bf16_t*)d_ws;
    bf16_t* giV  = ws + OFF_GIV;
    bf16_t* giE  = ws + OFF_GIE;
    bf16_t* hV   = ws + OFF_HV;
    bf16_t* hE   = ws + OFF_HE;
    bf16_t* vrep = ws + OFF_VREP;
    bf16_t* erep = ws + OFF_EREP;
    bf16_t* cvt  = ws + OFF_CVT;
    float*  out  = (float*)d_out;

    // downcast weights to bf16
    prep_kernel<<<3592, 256, 0, stream>>>(vertex_emb, edge_emb, v_Wi, e_Wi, v_Wh, e_Wh,
                                          vout_W, vrep_W, erep_W, cvt);

    // gi projections -> C-frag-major scatter layout
    gemm_bt<1, 2, 256, 32, bf16_t><<<dim3(16, 24), 256, 0, stream>>>(
        nullptr, cvt + CVT_VWI, v_bi, giV, input_vertex, cvt + CVT_VEMB, 1536);
    gemm_bt<2, 2, 512, 64, bf16_t><<<dim3(32, 24), 256, 0, stream>>>(
        nullptr, cvt + CVT_EWI, e_bi, giE, input_edge, cvt + CVT_EEMB, 1536);

    // fused vertex+edge GRU scans (one block per group, LDS exchange)
    gru_scan<<<16, 1024, 0, stream>>>(giV, giE, cvt + CVT_VWH, cvt + CVT_EWH,
                                      v_bh, e_bh, hV, hE);

    // output projections (rows b-major)
    gemm_bt<0, 1, 512, 32, float><<<dim3(16, 16), 256, 0, stream>>>(
        hV, cvt + CVT_VOUT, vout_b, out, nullptr, nullptr, 1024);
    gemm_bt<0, 0, 512, 32, bf16_t><<<dim3(16, 2), 256, 0, stream>>>(
        hV, cvt + CVT_VREPW, vrep_b, vrep, nullptr, nullptr, 128);
    gemm_bt<0, 0, 512, 64, bf16_t><<<dim3(32, 2), 256, 0, stream>>>(
        hE, cvt + CVT_EREPW, erep_b, erep, nullptr, nullptr, 128);

    etype_kernel<<<256, 256, 0, stream>>>(erep, etype_W, etype_b, out);
    attn_kernel<<<256, 256, 0, stream>>>(erep, vrep, src_w, src_b, dst_w, dst_b, out);
}

// Round 5
// 951.559 us; speedup vs baseline: 2.9119x; 2.9119x over previous
//
#include <hip/hip_runtime.h>
#include <hip/hip_bf16.h>

// ---------------------------------------------------------------------------
// RNN_17214228922840: GraphRNN-ish model. fp32 I/O, bf16 MFMA compute.
//   B=128, TV=32, TE=64, VOCAB=1024, EMB=256, H=512 (3H=1536), REPR=128, NET=8
// Outputs (flat, fp32): O_vertex [128,1024,32] | O_edge [128,32,2,64] | O_edge_type [128,8,64]
// Row spaces are b-major: row = b*T + t.
// gi layout (t-fast): [grp(8)][gate(3)][col(512)][r(16)][T]
// ---------------------------------------------------------------------------

typedef __bf16 bf16_t;
typedef bf16_t bf16x8 __attribute__((ext_vector_type(8)));
typedef bf16_t bf16x4 __attribute__((ext_vector_type(4)));
typedef float  f32x4  __attribute__((ext_vector_type(4)));

// workspace layout (bf16 element offsets)
#define OFF_GIV  0ull                    // 8*3*512*16*32 = 6291456
#define OFF_GIE  6291456ull              // 8*3*512*16*64 = 12582912
#define OFF_HV   18874368ull             // 128*32*512 (b-major)
#define OFF_HE   20971520ull             // 128*64*512 (b-major)
#define OFF_VREP 25165824ull             // 128*32*128
#define OFF_EREP 25690112ull             // 128*64*128
#define OFF_HBUF 26738688ull             // 16 slots * 2 parity * 8192
#define FLAG_BYTE_OFF 54001664ull        // 16 slots * 32 ints (poison 0xAA < 0 = self-reset)
#define OFF_CVT  27002880ull             // converted bf16 weights below
#define CVT_VEMB  0ull
#define CVT_EEMB  262144ull
#define CVT_VWI   270336ull
#define CVT_EWI   663552ull
#define CVT_VWH   1449984ull
#define CVT_EWH   2236416ull
#define CVT_VOUT  3022848ull
#define CVT_VREPW 3547136ull
#define CVT_EREPW 3612672ull

// output flat offsets (fp32 elements)
#define OUT_OV 0ull
#define OUT_OE 4194304ull
#define OUT_OT 4718592ull

__device__ __forceinline__ float fsigmoid(float x) {
    float e = __builtin_amdgcn_exp2f(-x * 1.4426950408889634f);
    return __builtin_amdgcn_rcpf(1.0f + e);
}
__device__ __forceinline__ float ftanh(float x) {
    x = fminf(x, 15.0f);
    float e = __builtin_amdgcn_exp2f(x * 2.8853900817779268f); // exp(2x)
    return (e - 1.0f) * __builtin_amdgcn_rcpf(e + 1.0f);
}

// ---------------------------------------------------------------------------
// prep: fp32 -> bf16 downcast of weights/embeddings (3592 blocks x 1024 elem)
// ---------------------------------------------------------------------------
__global__ __launch_bounds__(256) void prep_kernel(
    const float* __restrict__ vemb, const float* __restrict__ eemb,
    const float* __restrict__ vwi,  const float* __restrict__ ewi,
    const float* __restrict__ vwh,  const float* __restrict__ ewh,
    const float* __restrict__ voutw, const float* __restrict__ vrepw,
    const float* __restrict__ erepw, bf16_t* __restrict__ cvt)
{
    int blk = blockIdx.x;
    const float* src; bf16_t* dst; int lb;
    if (blk < 256)       { src = vemb;  dst = cvt + CVT_VEMB;  lb = blk; }
    else if (blk < 264)  { src = eemb;  dst = cvt + CVT_EEMB;  lb = blk - 256; }
    else if (blk < 648)  { src = vwi;   dst = cvt + CVT_VWI;   lb = blk - 264; }
    else if (blk < 1416) { src = ewi;   dst = cvt + CVT_EWI;   lb = blk - 648; }
    else if (blk < 2184) { src = vwh;   dst = cvt + CVT_VWH;   lb = blk - 1416; }
    else if (blk < 2952) { src = ewh;   dst = cvt + CVT_EWH;   lb = blk - 2184; }
    else if (blk < 3464) { src = voutw; dst = cvt + CVT_VOUT;  lb = blk - 2952; }
    else if (blk < 3528) { src = vrepw; dst = cvt + CVT_VREPW; lb = blk - 3464; }
    else                 { src = erepw; dst = cvt + CVT_EREPW; lb = blk - 3528; }
    int idx = lb * 1024 + threadIdx.x * 4;
    float4 v = *(const float4*)(src + idx);
    bf16x4 o;
    o[0] = (bf16_t)v.x; o[1] = (bf16_t)v.y; o[2] = (bf16_t)v.z; o[3] = (bf16_t)v.w;
    *(bf16x4*)(dst + idx) = o;
}

// ---------------------------------------------------------------------------
// Generic C = gather(A) @ W^T + bias GEMM. Wave computes 64x64 (4x4 MFMA tiles).
// Rows are b-major: row = b*TT + t.
// GATHER: 0 dense A[M,K]; 1 vertex emb gather (K=256); 2 edge emb pair (K=512)
// OUTMODE: 0 row-major C[row*N+col]
//          1 O_vertex: float4 at [(b*1024+col)*32 + t]
//          2 gi scatter (t-fast): bf16x4 at [((grp*3+gate)*512+cw)*16 + r]*TT + t
// ---------------------------------------------------------------------------
template<int GATHER, int OUTMODE, int K, int TT, typename CT>
__global__ __launch_bounds__(256) void gemm_bt(
    const bf16_t* __restrict__ A, const bf16_t* __restrict__ W,
    const float* __restrict__ bias, CT* __restrict__ C,
    const int* __restrict__ gidx, const bf16_t* __restrict__ emb, int N)
{
    constexpr int K32 = K / 32;
    const int tid = threadIdx.x, lane = tid & 63, wv = tid >> 6;
    const int r16 = lane & 15, quad = lane >> 4, koff = quad * 8;
    const int mbase = blockIdx.x * 256 + wv * 64;
    const int nbase = blockIdx.y * 64;

    const bf16_t* ap0[4];
    const bf16_t* ap1[4];
#pragma unroll
    for (int i = 0; i < 4; ++i) {
        int row = mbase + i * 16 + r16;
        if (GATHER == 0) {
            ap0[i] = A + (size_t)row * K + koff;
            ap1[i] = ap0[i];
        } else if (GATHER == 1) {
            int idx = gidx[row];                    // row = b*32+t
            ap0[i] = emb + (size_t)idx * 256 + koff;
            ap1[i] = ap0[i];
        } else {
            int c = row * 3;                        // row = b*64+t
            ap0[i] = emb + (size_t)gidx[c] * 256 + koff;
            ap1[i] = emb + (size_t)gidx[c + 1] * 256 + koff;
        }
    }
    const bf16_t* bp[4];
#pragma unroll
    for (int j = 0; j < 4; ++j)
        bp[j] = W + (size_t)(nbase + j * 16 + r16) * K + koff;

    f32x4 acc[4][4];
#pragma unroll
    for (int i = 0; i < 4; ++i)
#pragma unroll
        for (int j = 0; j < 4; ++j) acc[i][j] = (f32x4){0.f, 0.f, 0.f, 0.f};

    for (int kc = 0; kc < K32; ++kc) {
        bf16x8 a[4], b[4];
#pragma unroll
        for (int i = 0; i < 4; ++i) {
            const bf16_t* p;
            if (GATHER == 2) p = (kc < 8) ? (ap0[i] + kc * 32) : (ap1[i] + (kc - 8) * 32);
            else             p = ap0[i] + kc * 32;
            a[i] = *(const bf16x8*)p;
        }
#pragma unroll
        for (int j = 0; j < 4; ++j) b[j] = *(const bf16x8*)(bp[j] + kc * 32);
#pragma unroll
        for (int i = 0; i < 4; ++i)
#pragma unroll
            for (int j = 0; j < 4; ++j)
                acc[i][j] = __builtin_amdgcn_mfma_f32_16x16x32_bf16(a[i], b[j], acc[i][j], 0, 0, 0);
    }

#pragma unroll
    for (int j = 0; j < 4; ++j) {
        int col = nbase + j * 16 + r16;
        float bf = bias[col];
        int gate = col >> 9, cw = col & 511;        // OUTMODE 2 decomposition
#pragma unroll
        for (int i = 0; i < 4; ++i) {
            int rowq = mbase + i * 16 + quad * 4;   // 4 consecutive t in one b
            if (OUTMODE == 1) {
                int b = rowq >> 5, t0 = rowq & 31;
                float4 v4;
                v4.x = acc[i][j][0] + bf; v4.y = acc[i][j][1] + bf;
                v4.z = acc[i][j][2] + bf; v4.w = acc[i][j][3] + bf;
                *(float4*)((float*)C + ((size_t)(b * 1024) + col) * 32 + t0) = v4;
            } else if (OUTMODE == 2) {
                int b = rowq / TT, t0 = rowq & (TT - 1);
                int grp = b >> 4, r = b & 15;
                bf16x4 v4;
#pragma unroll
                for (int q = 0; q < 4; ++q) v4[q] = (bf16_t)(acc[i][j][q] + bf);
                *(bf16x4*)((bf16_t*)C +
                    ((size_t)(((grp * 3 + gate) * 512 + cw) * 16 + r)) * TT + t0) = v4;
            } else {
#pragma unroll
                for (int q = 0; q < 4; ++q) {
                    int row = rowq + q;
                    C[(size_t)row * N + col] = (CT)(acc[i][j][q] + bf);
                }
            }
        }
    }
}

// ---------------------------------------------------------------------------
// Fused GRU scans (vertex blocks 0..31, edge blocks 32..63).
// Block = 512 thr (8 waves). Group = 16 batch rows, 4 blocks (128 h-cols each;
// Wh slice register-resident: 192 regs/lane -> AGPR side of unified RF).
// Exchange protocol: h stores (MALL, sc0 sc1) -> s_waitcnt(0) -> per-wave flag
// store -> consumers 64-lane __all poll on 32 wave-flags; hout stores issued
// AFTER the flag so their HBM latency overlaps the poll. No atomics-RMW, no
// inter-block fence, no in-loop tid0 serialization. Flags self-reset via ws
// poison (0xAA... < 0).
// ---------------------------------------------------------------------------
__global__ __launch_bounds__(512) void gru_scan(
    const bf16_t* __restrict__ giV, const bf16_t* __restrict__ giE,
    const bf16_t* __restrict__ WhV, const bf16_t* __restrict__ WhE,
    const float* __restrict__ bhV, const float* __restrict__ bhE,
    bf16_t* __restrict__ hV, bf16_t* __restrict__ hE,
    bf16_t* __restrict__ hbuf, int* __restrict__ flags)
{
    const int blk  = blockIdx.x;
    const int role = blk >> 5;          // 0 vertex, 1 edge
    const int lb   = blk & 31;
    const int g    = lb & 7;            // batch group; group's blocks == g (mod 8)
    const int s    = lb >> 3;           // col-slice 0..3
    const bf16_t* gi = role ? giE : giV;
    const bf16_t* Wh = role ? WhE : WhV;
    const float*  bh = role ? bhE : bhV;
    bf16_t* hout = role ? hE : hV;
    const int T = role ? 64 : 32;
    const int slot = role * 8 + g;
    bf16_t* buf0 = hbuf + (size_t)slot * 2 * 8192;
    int* fl = flags + slot * 32;
    const int bb = g * 16;

    const int tid = threadIdx.x, lane = tid & 63, wv = tid >> 6;
    const int r16 = lane & 15, quad = lane >> 4, koff = quad * 8;
    const int j = s * 128 + wv * 16 + r16;   // this lane's h column (0..511)

    // --- Wh slice in registers: wfrag[gate][kc] (192 regs) ---
    bf16x8 wfrag[3][16];
#pragma unroll
    for (int gate = 0; gate < 3; ++gate) {
        const bf16_t* wrow = Wh + ((size_t)(gate * 512 + j)) * 512 + koff;
#pragma unroll
        for (int kc = 0; kc < 16; ++kc)
            wfrag[gate][kc] = *(const bf16x8*)(wrow + kc * 32);
    }
    const float bhr = bh[j], bhz = bh[512 + j], bhn = bh[1024 + j];
    float hq[4] = {0.f, 0.f, 0.f, 0.f};

    __shared__ __align__(16) bf16_t hbf[2][16][520];
    for (int i = tid; i < 16 * 512; i += 512)
        hbf[0][i >> 9][i & 511] = (bf16_t)0.f;

    for (int t = 0; t < T; ++t) {
        // gi prefetch (t-fast layout): 12 scalar loads, issued before the poll
        float gv[3][4];
#pragma unroll
        for (int gg = 0; gg < 3; ++gg)
#pragma unroll
            for (int q = 0; q < 4; ++q)
                gv[gg][q] = (float)gi[((size_t)(((g * 3 + gg) * 512 + j) * 16 + quad * 4 + q)) * T + t];

        if (t > 0) {
            // per-wave spin: all 32 waves of the group arrived step t-1
            while (!__all(__hip_atomic_load(&fl[lane & 31], __ATOMIC_RELAXED,
                                            __HIP_MEMORY_SCOPE_AGENT) >= t)) { }
            asm volatile("" ::: "memory");
            // h(t) [16x512 bf16] from MALL -> LDS parity t&1
            unsigned long long* src = (unsigned long long*)(buf0 + (size_t)(t & 1) * 8192);
#pragma unroll
            for (int it = 0; it < 4; ++it) {
                int c = tid + it * 512;
                int row = c >> 7, unit = c & 127;
                unsigned long long v = __hip_atomic_load(src + c, __ATOMIC_RELAXED,
                                                         __HIP_MEMORY_SCOPE_AGENT);
                *(unsigned long long*)&hbf[t & 1][row][unit * 4] = v;
            }
        }
        __syncthreads();

        // MFMA: gh for this lane's 16-col strip, 3 gates
        const bf16_t (*cur)[520] = hbf[t & 1];
        f32x4 ar = {0.f,0.f,0.f,0.f}, az = {0.f,0.f,0.f,0.f}, an = {0.f,0.f,0.f,0.f};
#pragma unroll
        for (int kc = 0; kc < 16; ++kc) {
            bf16x8 a = *(const bf16x8*)&cur[r16][kc * 32 + koff];
            ar = __builtin_amdgcn_mfma_f32_16x16x32_bf16(a, wfrag[0][kc], ar, 0, 0, 0);
            az = __builtin_amdgcn_mfma_f32_16x16x32_bf16(a, wfrag[1][kc], az, 0, 0, 0);
            an = __builtin_amdgcn_mfma_f32_16x16x32_bf16(a, wfrag[2][kc], an, 0, 0, 0);
        }

        // gates + h update (C-frag: col=lane&15, row=quad*4+q)
        bf16_t hb4[4];
#pragma unroll
        for (int q = 0; q < 4; ++q) {
            float r = fsigmoid(gv[0][q] + ar[q] + bhr);
            float z = fsigmoid(gv[1][q] + az[q] + bhz);
            float n = ftanh(gv[2][q] + r * (an[q] + bhn));
            float hnew = (1.0f - z) * n + z * hq[q];
            hq[q] = hnew;
            hb4[q] = (bf16_t)hnew;
        }

        if (t + 1 < T) {
            // release: h -> MALL, drain, then flag
            bf16_t* dstg = buf0 + (size_t)((t + 1) & 1) * 8192;
#pragma unroll
            for (int q = 0; q < 4; ++q)
                __hip_atomic_store((unsigned short*)(dstg + (quad * 4 + q) * 512 + j),
                                   __builtin_bit_cast(unsigned short, hb4[q]),
                                   __ATOMIC_RELAXED, __HIP_MEMORY_SCOPE_AGENT);
            __builtin_amdgcn_s_waitcnt(0);
            if (lane == 0)
                __hip_atomic_store(&fl[s * 8 + wv], t + 1,
                                   __ATOMIC_RELAXED, __HIP_MEMORY_SCOPE_AGENT);
        }
        // hout (HBM) after the flag: latency overlaps the next poll
#pragma unroll
        for (int q = 0; q < 4; ++q)
            hout[((size_t)((bb + quad * 4 + q) * T + t)) * 512 + j] = hb4[q];
    }
}

// O_edge_type[b,k,te] = erep[b,te,:] . etype_W[k,:] + etype_b[k]
__global__ __launch_bounds__(256) void etype_kernel(
    const bf16_t* __restrict__ erep, const float* __restrict__ W,
    const float* __restrict__ bias, float* __restrict__ out)
{
    int o = blockIdx.x * 256 + threadIdx.x;      // 65536 outputs
    int te = o & 63, k = (o >> 6) & 7, b = o >> 9;
    float sacc = bias[k];
    const bf16_t* e = erep + ((size_t)(b * 64 + te)) * 128;
    const float* w = W + k * 128;
#pragma unroll 8
    for (int r = 0; r < 128; ++r) sacc += (float)e[r] * w[r];
    out[OUT_OT + o] = sacc;
}

// O_edge[b,tv,{0,1},te] = sum_r tanh(e[b,te,r]+v[b,tv,r]) * {src,dst}_w[r] + b
__global__ __launch_bounds__(256) void attn_kernel(
    const bf16_t* __restrict__ erep, const bf16_t* __restrict__ vrep,
    const float* __restrict__ src_w, const float* __restrict__ src_b,
    const float* __restrict__ dst_w, const float* __restrict__ dst_b,
    float* __restrict__ out)
{
    int b = blockIdx.x >> 1, half = blockIdx.x & 1;
    __shared__ float es[32][129], vs[32][129], swf[128], dwf[128];
    int tid = threadIdx.x;
    for (int f = tid; f < 32 * 128; f += 256) {
        int i = f >> 7, r = f & 127;
        es[i][r] = (float)erep[((size_t)(b * 64 + half * 32 + i)) * 128 + r];
        vs[i][r] = (float)vrep[((size_t)(b * 32 + i)) * 128 + r];
    }
    if (tid < 128) { swf[tid] = src_w[tid]; dwf[tid] = dst_w[tid]; }
    __syncthreads();
    float sb = src_b[0], db = dst_b[0];
    for (int p = tid; p < 1024; p += 256) {
        int te = p & 31, tv = p >> 5;
        float sacc = 0.f, dacc = 0.f;
#pragma unroll 4
        for (int r = 0; r < 128; ++r) {
            float u = ftanh(es[te][r] + vs[tv][r]);
            sacc += u * swf[r];
            dacc += u * dwf[r];
        }
        int teg = half * 32 + te;
        size_t base = OUT_OE + ((size_t)(b * 32 + tv) * 2) * 64;
        out[base + teg]      = sacc + sb;
        out[base + 64 + teg] = dacc + db;
    }
}

extern "C" void kernel_launch(void* const* d_in, const int* in_sizes, int n_in,
                              void* d_out, int out_size, void* d_ws, size_t ws_size,
                              hipStream_t stream)
{
    const int*   input_vertex = (const int*)d_in[0];
    const int*   input_edge   = (const int*)d_in[1];
    const float* vertex_emb   = (const float*)d_in[2];
    const float* v_Wi  = (const float*)d_in[3];
    const float* v_Wh  = (const float*)d_in[4];
    const float* v_bi  = (const float*)d_in[5];
    const float* v_bh  = (const float*)d_in[6];
    const float* vout_W = (const float*)d_in[7];
    const float* vout_b = (const float*)d_in[8];
    const float* vrep_W = (const float*)d_in[9];
    const float* vrep_b = (const float*)d_in[10];
    const float* edge_emb = (const float*)d_in[11];
    const float* e_Wi  = (const float*)d_in[12];
    const float* e_Wh  = (const float*)d_in[13];
    const float* e_bi  = (const float*)d_in[14];
    const float* e_bh  = (const float*)d_in[15];
    const float* erep_W = (const float*)d_in[16];
    const float* erep_b = (const float*)d_in[17];
    const float* etype_W = (const float*)d_in[18];
    const float* etype_b = (const float*)d_in[19];
    const float* src_w = (const float*)d_in[20];
    const float* src_b = (const float*)d_in[21];
    const float* dst_w = (const float*)d_in[22];
    const float* dst_b = (const float*)d_in[23];

    bf16_t* ws   = (bf16_t*)d_ws;
    bf16_t* giV  = ws + OFF_GIV;
    bf16_t* giE  = ws + OFF_GIE;
    bf16_t* hV   = ws + OFF_HV;
    bf16_t* hE   = ws + OFF_HE;
    bf16_t* vrep = ws + OFF_VREP;
    bf16_t* erep = ws + OFF_EREP;
    bf16_t* hbuf = ws + OFF_HBUF;
    bf16_t* cvt  = ws + OFF_CVT;
    int*    flags = (int*)((char*)d_ws + FLAG_BYTE_OFF);
    float*  out  = (float*)d_out;

    // downcast weights to bf16 (flags need no init: 0xAA poison is negative)
    prep_kernel<<<3592, 256, 0, stream>>>(vertex_emb, edge_emb, v_Wi, e_Wi, v_Wh, e_Wh,
                                          vout_W, vrep_W, erep_W, cvt);

    // gi projections -> t-fast scatter layout
    gemm_bt<1, 2, 256, 32, bf16_t><<<dim3(16, 24), 256, 0, stream>>>(
        nullptr, cvt + CVT_VWI, v_bi, giV, input_vertex, cvt + CVT_VEMB, 1536);
    gemm_bt<2, 2, 512, 64, bf16_t><<<dim3(32, 24), 256, 0, stream>>>(
        nullptr, cvt + CVT_EWI, e_bi, giE, input_edge, cvt + CVT_EEMB, 1536);

    // fused vertex+edge GRU scans (4 blocks per group, wave-flag exchange)
    gru_scan<<<64, 512, 0, stream>>>(giV, giE, cvt + CVT_VWH, cvt + CVT_EWH,
                                     v_bh, e_bh, hV, hE, hbuf, flags);

    // output projections (rows b-major)
    gemm_bt<0, 1, 512, 32, float><<<dim3(16, 16), 256, 0, stream>>>(
        hV, cvt + CVT_VOUT, vout_b, out, nullptr, nullptr, 1024);
    gemm_bt<0, 0, 512, 32, bf16_t><<<dim3(16, 2), 256, 0, stream>>>(
        hV, cvt + CVT_VREPW, vrep_b, vrep, nullptr, nullptr, 128);
    gemm_bt<0, 0, 512, 64, bf16_t><<<dim3(32, 2), 256, 0, stream>>>(
        hE, cvt + CVT_EREPW, erep_b, erep, nullptr, nullptr, 128);

    etype_kernel<<<256, 256, 0, stream>>>(erep, etype_W, etype_b, out);
    attn_kernel<<<256, 256, 0, stream>>>(erep, vrep, src_w, src_b, dst_w, dst_b, out);
}

// Round 6
// 839.595 us; speedup vs baseline: 3.3002x; 1.1334x over previous
//
#include <hip/hip_runtime.h>
#include <hip/hip_bf16.h>

// ---------------------------------------------------------------------------
// RNN_17214228922840: GraphRNN-ish model. fp32 I/O, bf16 MFMA compute.
//   B=128, TV=32, TE=64, VOCAB=1024, EMB=256, H=512 (3H=1536), REPR=128, NET=8
// Outputs (flat, fp32): O_vertex [128,1024,32] | O_edge [128,32,2,64] | O_edge_type [128,8,64]
// Row spaces are b-major: row = b*T + t.
// gi layout (t-fast): [grp(8)][gate(3)][col(512)][r(16)][T]
// ---------------------------------------------------------------------------

typedef __bf16 bf16_t;
typedef bf16_t bf16x8 __attribute__((ext_vector_type(8)));
typedef bf16_t bf16x4 __attribute__((ext_vector_type(4)));
typedef float  f32x4  __attribute__((ext_vector_type(4)));

// workspace layout (bf16 element offsets)
#define OFF_GIV  0ull                    // 8*3*512*16*32 = 6291456
#define OFF_GIE  6291456ull              // 8*3*512*16*64 = 12582912
#define OFF_HV   18874368ull             // 128*32*512 (b-major)
#define OFF_HE   20971520ull             // 128*64*512 (b-major)
#define OFF_VREP 25165824ull             // 128*32*128
#define OFF_EREP 25690112ull             // 128*64*128
#define OFF_HBUF 26738688ull             // 16 slots * 2 parity * 8192
#define FLAG_BYTE_OFF 54001664ull        // 16 slots * 4 ints (poison 0xAA < 0 = self-reset)
#define OFF_CVT  27002880ull             // converted bf16 weights below
#define CVT_VEMB  0ull
#define CVT_EEMB  262144ull
#define CVT_VWI   270336ull
#define CVT_EWI   663552ull
#define CVT_VWH   1449984ull
#define CVT_EWH   2236416ull
#define CVT_VOUT  3022848ull
#define CVT_VREPW 3547136ull
#define CVT_EREPW 3612672ull

// output flat offsets (fp32 elements)
#define OUT_OV 0ull
#define OUT_OE 4194304ull
#define OUT_OT 4718592ull

__device__ __forceinline__ float fsigmoid(float x) {
    float e = __builtin_amdgcn_exp2f(-x * 1.4426950408889634f);
    return __builtin_amdgcn_rcpf(1.0f + e);
}
__device__ __forceinline__ float ftanh(float x) {
    x = fminf(x, 15.0f);
    float e = __builtin_amdgcn_exp2f(x * 2.8853900817779268f); // exp(2x)
    return (e - 1.0f) * __builtin_amdgcn_rcpf(e + 1.0f);
}

// ---------------------------------------------------------------------------
// prep: fp32 -> bf16 downcast of weights/embeddings (3592 blocks x 1024 elem)
// ---------------------------------------------------------------------------
__global__ __launch_bounds__(256) void prep_kernel(
    const float* __restrict__ vemb, const float* __restrict__ eemb,
    const float* __restrict__ vwi,  const float* __restrict__ ewi,
    const float* __restrict__ vwh,  const float* __restrict__ ewh,
    const float* __restrict__ voutw, const float* __restrict__ vrepw,
    const float* __restrict__ erepw, bf16_t* __restrict__ cvt)
{
    int blk = blockIdx.x;
    const float* src; bf16_t* dst; int lb;
    if (blk < 256)       { src = vemb;  dst = cvt + CVT_VEMB;  lb = blk; }
    else if (blk < 264)  { src = eemb;  dst = cvt + CVT_EEMB;  lb = blk - 256; }
    else if (blk < 648)  { src = vwi;   dst = cvt + CVT_VWI;   lb = blk - 264; }
    else if (blk < 1416) { src = ewi;   dst = cvt + CVT_EWI;   lb = blk - 648; }
    else if (blk < 2184) { src = vwh;   dst = cvt + CVT_VWH;   lb = blk - 1416; }
    else if (blk < 2952) { src = ewh;   dst = cvt + CVT_EWH;   lb = blk - 2184; }
    else if (blk < 3464) { src = voutw; dst = cvt + CVT_VOUT;  lb = blk - 2952; }
    else if (blk < 3528) { src = vrepw; dst = cvt + CVT_VREPW; lb = blk - 3464; }
    else                 { src = erepw; dst = cvt + CVT_EREPW; lb = blk - 3528; }
    int idx = lb * 1024 + threadIdx.x * 4;
    float4 v = *(const float4*)(src + idx);
    bf16x4 o;
    o[0] = (bf16_t)v.x; o[1] = (bf16_t)v.y; o[2] = (bf16_t)v.z; o[3] = (bf16_t)v.w;
    *(bf16x4*)(dst + idx) = o;
}

// ---------------------------------------------------------------------------
// Generic C = gather(A) @ W^T + bias GEMM. Wave computes 64x64 (4x4 MFMA tiles).
// Rows are b-major: row = b*TT + t.
// GATHER: 0 dense A[M,K]; 1 vertex emb gather (K=256); 2 edge emb pair (K=512)
// OUTMODE: 0 row-major C[row*N+col]
//          1 O_vertex: float4 at [(b*1024+col)*32 + t]
//          2 gi scatter (t-fast): bf16x4 at [((grp*3+gate)*512+cw)*16 + r]*TT + t
// ---------------------------------------------------------------------------
template<int GATHER, int OUTMODE, int K, int TT, typename CT>
__global__ __launch_bounds__(256) void gemm_bt(
    const bf16_t* __restrict__ A, const bf16_t* __restrict__ W,
    const float* __restrict__ bias, CT* __restrict__ C,
    const int* __restrict__ gidx, const bf16_t* __restrict__ emb, int N)
{
    constexpr int K32 = K / 32;
    const int tid = threadIdx.x, lane = tid & 63, wv = tid >> 6;
    const int r16 = lane & 15, quad = lane >> 4, koff = quad * 8;
    const int mbase = blockIdx.x * 256 + wv * 64;
    const int nbase = blockIdx.y * 64;

    const bf16_t* ap0[4];
    const bf16_t* ap1[4];
#pragma unroll
    for (int i = 0; i < 4; ++i) {
        int row = mbase + i * 16 + r16;
        if (GATHER == 0) {
            ap0[i] = A + (size_t)row * K + koff;
            ap1[i] = ap0[i];
        } else if (GATHER == 1) {
            int idx = gidx[row];                    // row = b*32+t
            ap0[i] = emb + (size_t)idx * 256 + koff;
            ap1[i] = ap0[i];
        } else {
            int c = row * 3;                        // row = b*64+t
            ap0[i] = emb + (size_t)gidx[c] * 256 + koff;
            ap1[i] = emb + (size_t)gidx[c + 1] * 256 + koff;
        }
    }
    const bf16_t* bp[4];
#pragma unroll
    for (int j = 0; j < 4; ++j)
        bp[j] = W + (size_t)(nbase + j * 16 + r16) * K + koff;

    f32x4 acc[4][4];
#pragma unroll
    for (int i = 0; i < 4; ++i)
#pragma unroll
        for (int j = 0; j < 4; ++j) acc[i][j] = (f32x4){0.f, 0.f, 0.f, 0.f};

    for (int kc = 0; kc < K32; ++kc) {
        bf16x8 a[4], b[4];
#pragma unroll
        for (int i = 0; i < 4; ++i) {
            const bf16_t* p;
            if (GATHER == 2) p = (kc < 8) ? (ap0[i] + kc * 32) : (ap1[i] + (kc - 8) * 32);
            else             p = ap0[i] + kc * 32;
            a[i] = *(const bf16x8*)p;
        }
#pragma unroll
        for (int j = 0; j < 4; ++j) b[j] = *(const bf16x8*)(bp[j] + kc * 32);
#pragma unroll
        for (int i = 0; i < 4; ++i)
#pragma unroll
            for (int j = 0; j < 4; ++j)
                acc[i][j] = __builtin_amdgcn_mfma_f32_16x16x32_bf16(a[i], b[j], acc[i][j], 0, 0, 0);
    }

#pragma unroll
    for (int j = 0; j < 4; ++j) {
        int col = nbase + j * 16 + r16;
        float bf = bias[col];
        int gate = col >> 9, cw = col & 511;        // OUTMODE 2 decomposition
#pragma unroll
        for (int i = 0; i < 4; ++i) {
            int rowq = mbase + i * 16 + quad * 4;   // 4 consecutive t in one b
            if (OUTMODE == 1) {
                int b = rowq >> 5, t0 = rowq & 31;
                float4 v4;
                v4.x = acc[i][j][0] + bf; v4.y = acc[i][j][1] + bf;
                v4.z = acc[i][j][2] + bf; v4.w = acc[i][j][3] + bf;
                *(float4*)((float*)C + ((size_t)(b * 1024) + col) * 32 + t0) = v4;
            } else if (OUTMODE == 2) {
                int b = rowq / TT, t0 = rowq & (TT - 1);
                int grp = b >> 4, r = b & 15;
                bf16x4 v4;
#pragma unroll
                for (int q = 0; q < 4; ++q) v4[q] = (bf16_t)(acc[i][j][q] + bf);
                *(bf16x4*)((bf16_t*)C +
                    ((size_t)(((grp * 3 + gate) * 512 + cw) * 16 + r)) * TT + t0) = v4;
            } else {
#pragma unroll
                for (int q = 0; q < 4; ++q) {
                    int row = rowq + q;
                    C[(size_t)row * N + col] = (CT)(acc[i][j][q] + bf);
                }
            }
        }
    }
}

// ---------------------------------------------------------------------------
// Fused GRU scans (vertex blocks 0..31, edge blocks 32..63).
// Block = 512 thr (8 waves). Group = 16 batch rows, 4 blocks (128 h-cols each;
// Wh slice register-resident: 192 regs/lane on unified VGPR/AGPR file).
// Exchange: own slice written straight to next-parity LDS; remote 3 slices via
// MALL (agent scope). Release = h stores -> s_waitcnt(0) -> __syncthreads ->
// tid0 stores per-BLOCK flag (idempotent, self-init from 0xAA poison).
// Acquire = per-wave poll of the 4 block flags: ONE 16B segment per spin
// iteration (R5's 32-flag x 64-lane poll flooded the fabric: 520 MB FETCH).
// hout (HBM history) issued after the flag, overlaps the next poll.
// ---------------------------------------------------------------------------
__global__ __launch_bounds__(512) void gru_scan(
    const bf16_t* __restrict__ giV, const bf16_t* __restrict__ giE,
    const bf16_t* __restrict__ WhV, const bf16_t* __restrict__ WhE,
    const float* __restrict__ bhV, const float* __restrict__ bhE,
    bf16_t* __restrict__ hV, bf16_t* __restrict__ hE,
    bf16_t* __restrict__ hbuf, int* __restrict__ flags)
{
    const int blk  = blockIdx.x;
    const int role = blk >> 5;          // 0 vertex, 1 edge
    const int lb   = blk & 31;
    const int g    = lb & 7;            // batch group; group's blocks == g (mod 8)
    const int s    = lb >> 3;           // col-slice 0..3
    const bf16_t* gi = role ? giE : giV;
    const bf16_t* Wh = role ? WhE : WhV;
    const float*  bh = role ? bhE : bhV;
    bf16_t* hout = role ? hE : hV;
    const int T = role ? 64 : 32;
    const int slot = role * 8 + g;
    bf16_t* buf0 = hbuf + (size_t)slot * 2 * 8192;
    int* fl = flags + slot * 4;
    const int bb = g * 16;

    const int tid = threadIdx.x, lane = tid & 63, wv = tid >> 6;
    const int r16 = lane & 15, quad = lane >> 4, koff = quad * 8;
    const int j = s * 128 + wv * 16 + r16;   // this lane's h column (0..511)
    const int rs0 = (s + 1) & 3, rs1 = (s + 2) & 3, rs2 = (s + 3) & 3;

    // --- Wh slice in registers: wfrag[gate][kc] (192 regs) ---
    bf16x8 wfrag[3][16];
#pragma unroll
    for (int gate = 0; gate < 3; ++gate) {
        const bf16_t* wrow = Wh + ((size_t)(gate * 512 + j)) * 512 + koff;
#pragma unroll
        for (int kc = 0; kc < 16; ++kc)
            wfrag[gate][kc] = *(const bf16x8*)(wrow + kc * 32);
    }
    const float bhr = bh[j], bhz = bh[512 + j], bhn = bh[1024 + j];
    float hq[4] = {0.f, 0.f, 0.f, 0.f};

    __shared__ __align__(16) bf16_t hbf[2][16][520];
    for (int i = tid; i < 16 * 512; i += 512)
        hbf[0][i >> 9][i & 511] = (bf16_t)0.f;   // h(0)=0; ordered by first barrier

    const int arow = tid >> 5, au = tid & 31;    // phase-A unit: row 0..15, 8B unit 0..31

    for (int t = 0; t < T; ++t) {
        // gi prefetch (t-fast layout): 12 scalar loads, issued before the poll
        float gv[3][4];
#pragma unroll
        for (int gg = 0; gg < 3; ++gg)
#pragma unroll
            for (int q = 0; q < 4; ++q)
                gv[gg][q] = (float)gi[((size_t)(((g * 3 + gg) * 512 + j) * 16 + quad * 4 + q)) * T + t];

        if (t > 0) {
            // acquire: poll the 4 per-block flags (one 16B segment per iter)
            while (!__all((int)(__hip_atomic_load(&fl[lane & 3], __ATOMIC_RELAXED,
                                                  __HIP_MEMORY_SCOPE_AGENT) >= t))) { }
            asm volatile("" ::: "memory");
            // remote 3 slices of h(t) -> LDS parity t&1 (own slice already there)
            unsigned long long* src = (unsigned long long*)(buf0 + (size_t)(t & 1) * 8192);
            unsigned long long vv[3];
            vv[0] = __hip_atomic_load(src + arow * 128 + rs0 * 32 + au, __ATOMIC_RELAXED, __HIP_MEMORY_SCOPE_AGENT);
            vv[1] = __hip_atomic_load(src + arow * 128 + rs1 * 32 + au, __ATOMIC_RELAXED, __HIP_MEMORY_SCOPE_AGENT);
            vv[2] = __hip_atomic_load(src + arow * 128 + rs2 * 32 + au, __ATOMIC_RELAXED, __HIP_MEMORY_SCOPE_AGENT);
            *(unsigned long long*)&hbf[t & 1][arow][rs0 * 128 + au * 4] = vv[0];
            *(unsigned long long*)&hbf[t & 1][arow][rs1 * 128 + au * 4] = vv[1];
            *(unsigned long long*)&hbf[t & 1][arow][rs2 * 128 + au * 4] = vv[2];
        }
        __syncthreads();

        // MFMA: gh for this lane's 16-col strip, 3 gates
        const bf16_t (*cur)[520] = hbf[t & 1];
        f32x4 ar = {0.f,0.f,0.f,0.f}, az = {0.f,0.f,0.f,0.f}, an = {0.f,0.f,0.f,0.f};
#pragma unroll
        for (int kc = 0; kc < 16; ++kc) {
            bf16x8 a = *(const bf16x8*)&cur[r16][kc * 32 + koff];
            ar = __builtin_amdgcn_mfma_f32_16x16x32_bf16(a, wfrag[0][kc], ar, 0, 0, 0);
            az = __builtin_amdgcn_mfma_f32_16x16x32_bf16(a, wfrag[1][kc], az, 0, 0, 0);
            an = __builtin_amdgcn_mfma_f32_16x16x32_bf16(a, wfrag[2][kc], an, 0, 0, 0);
        }

        // gates + h update (C-frag: col=lane&15, row=quad*4+q)
        bf16_t hb4[4];
#pragma unroll
        for (int q = 0; q < 4; ++q) {
            float r = fsigmoid(gv[0][q] + ar[q] + bhr);
            float z = fsigmoid(gv[1][q] + az[q] + bhz);
            float n = ftanh(gv[2][q] + r * (an[q] + bhn));
            float hnew = (1.0f - z) * n + z * hq[q];
            hq[q] = hnew;
            hb4[q] = (bf16_t)hnew;
        }

        // own slice of h(t+1) -> next-parity LDS (never round-trips MALL)
        bf16_t (*nxt)[520] = hbf[(t + 1) & 1];
#pragma unroll
        for (int q = 0; q < 4; ++q) nxt[quad * 4 + q][j] = hb4[q];

        if (t + 1 < T) {
            // release: h(t+1) remote-visible via MALL, drain, barrier, flag
            bf16_t* dstg = buf0 + (size_t)((t + 1) & 1) * 8192;
#pragma unroll
            for (int q = 0; q < 4; ++q)
                __hip_atomic_store((unsigned short*)(dstg + (quad * 4 + q) * 512 + j),
                                   __builtin_bit_cast(unsigned short, hb4[q]),
                                   __ATOMIC_RELAXED, __HIP_MEMORY_SCOPE_AGENT);
            __builtin_amdgcn_s_waitcnt(0);
            __syncthreads();
            if (tid == 0)
                __hip_atomic_store(&fl[s], t + 1,
                                   __ATOMIC_RELAXED, __HIP_MEMORY_SCOPE_AGENT);
        } else {
            __syncthreads();
        }
        // hout (HBM) after the flag: latency overlaps the next poll
#pragma unroll
        for (int q = 0; q < 4; ++q)
            hout[((size_t)((bb + quad * 4 + q) * T + t)) * 512 + j] = hb4[q];
    }
}

// O_edge_type[b,k,te] = erep[b,te,:] . etype_W[k,:] + etype_b[k]
__global__ __launch_bounds__(256) void etype_kernel(
    const bf16_t* __restrict__ erep, const float* __restrict__ W,
    const float* __restrict__ bias, float* __restrict__ out)
{
    int o = blockIdx.x * 256 + threadIdx.x;      // 65536 outputs
    int te = o & 63, k = (o >> 6) & 7, b = o >> 9;
    float sacc = bias[k];
    const bf16_t* e = erep + ((size_t)(b * 64 + te)) * 128;
    const float* w = W + k * 128;
#pragma unroll 8
    for (int r = 0; r < 128; ++r) sacc += (float)e[r] * w[r];
    out[OUT_OT + o] = sacc;
}

// O_edge[b,tv,{0,1},te] = sum_r tanh(e[b,te,r]+v[b,tv,r]) * {src,dst}_w[r] + b
__global__ __launch_bounds__(256) void attn_kernel(
    const bf16_t* __restrict__ erep, const bf16_t* __restrict__ vrep,
    const float* __restrict__ src_w, const float* __restrict__ src_b,
    const float* __restrict__ dst_w, const float* __restrict__ dst_b,
    float* __restrict__ out)
{
    int b = blockIdx.x >> 1, half = blockIdx.x & 1;
    __shared__ float es[32][129], vs[32][129], swf[128], dwf[128];
    int tid = threadIdx.x;
    for (int f = tid; f < 32 * 128; f += 256) {
        int i = f >> 7, r = f & 127;
        es[i][r] = (float)erep[((size_t)(b * 64 + half * 32 + i)) * 128 + r];
        vs[i][r] = (float)vrep[((size_t)(b * 32 + i)) * 128 + r];
    }
    if (tid < 128) { swf[tid] = src_w[tid]; dwf[tid] = dst_w[tid]; }
    __syncthreads();
    float sb = src_b[0], db = dst_b[0];
    for (int p = tid; p < 1024; p += 256) {
        int te = p & 31, tv = p >> 5;
        float sacc = 0.f, dacc = 0.f;
#pragma unroll 4
        for (int r = 0; r < 128; ++r) {
            float u = ftanh(es[te][r] + vs[tv][r]);
            sacc += u * swf[r];
            dacc += u * dwf[r];
        }
        int teg = half * 32 + te;
        size_t base = OUT_OE + ((size_t)(b * 32 + tv) * 2) * 64;
        out[base + teg]      = sacc + sb;
        out[base + 64 + teg] = dacc + db;
    }
}

extern "C" void kernel_launch(void* const* d_in, const int* in_sizes, int n_in,
                              void* d_out, int out_size, void* d_ws, size_t ws_size,
                              hipStream_t stream)
{
    const int*   input_vertex = (const int*)d_in[0];
    const int*   input_edge   = (const int*)d_in[1];
    const float* vertex_emb   = (const float*)d_in[2];
    const float* v_Wi  = (const float*)d_in[3];
    const float* v_Wh  = (const float*)d_in[4];
    const float* v_bi  = (const float*)d_in[5];
    const float* v_bh  = (const float*)d_in[6];
    const float* vout_W = (const float*)d_in[7];
    const float* vout_b = (const float*)d_in[8];
    const float* vrep_W = (const float*)d_in[9];
    const float* vrep_b = (const float*)d_in[10];
    const float* edge_emb = (const float*)d_in[11];
    const float* e_Wi  = (const float*)d_in[12];
    const float* e_Wh  = (const float*)d_in[13];
    const float* e_bi  = (const float*)d_in[14];
    const float* e_bh  = (const float*)d_in[15];
    const float* erep_W = (const float*)d_in[16];
    const float* erep_b = (const float*)d_in[17];
    const float* etype_W = (const float*)d_in[18];
    const float* etype_b = (const float*)d_in[19];
    const float* src_w = (const float*)d_in[20];
    const float* src_b = (const float*)d_in[21];
    const float* dst_w = (const float*)d_in[22];
    const float* dst_b = (const float*)d_in[23];

    bf16_t* ws   = (bf16_t*)d_ws;
    bf16_t* giV  = ws + OFF_GIV;
    bf16_t* giE  = ws + OFF_GIE;
    bf16_t* hV   = ws + OFF_HV;
    bf16_t* hE   = ws + OFF_HE;
    bf16_t* vrep = ws + OFF_VREP;
    bf16_t* erep = ws + OFF_EREP;
    bf16_t* hbuf = ws + OFF_HBUF;
    bf16_t* cvt  = ws + OFF_CVT;
    int*    flags = (int*)((char*)d_ws + FLAG_BYTE_OFF);
    float*  out  = (float*)d_out;

    // downcast weights to bf16 (flags need no init: 0xAA poison is negative)
    prep_kernel<<<3592, 256, 0, stream>>>(vertex_emb, edge_emb, v_Wi, e_Wi, v_Wh, e_Wh,
                                          vout_W, vrep_W, erep_W, cvt);

    // gi projections -> t-fast scatter layout
    gemm_bt<1, 2, 256, 32, bf16_t><<<dim3(16, 24), 256, 0, stream>>>(
        nullptr, cvt + CVT_VWI, v_bi, giV, input_vertex, cvt + CVT_VEMB, 1536);
    gemm_bt<2, 2, 512, 64, bf16_t><<<dim3(32, 24), 256, 0, stream>>>(
        nullptr, cvt + CVT_EWI, e_bi, giE, input_edge, cvt + CVT_EEMB, 1536);

    // fused vertex+edge GRU scans (4 blocks per group, per-block flag exchange)
    gru_scan<<<64, 512, 0, stream>>>(giV, giE, cvt + CVT_VWH, cvt + CVT_EWH,
                                     v_bh, e_bh, hV, hE, hbuf, flags);

    // output projections (rows b-major)
    gemm_bt<0, 1, 512, 32, float><<<dim3(16, 16), 256, 0, stream>>>(
        hV, cvt + CVT_VOUT, vout_b, out, nullptr, nullptr, 1024);
    gemm_bt<0, 0, 512, 32, bf16_t><<<dim3(16, 2), 256, 0, stream>>>(
        hV, cvt + CVT_VREPW, vrep_b, vrep, nullptr, nullptr, 128);
    gemm_bt<0, 0, 512, 64, bf16_t><<<dim3(32, 2), 256, 0, stream>>>(
        hE, cvt + CVT_EREPW, erep_b, erep, nullptr, nullptr, 128);

    etype_kernel<<<256, 256, 0, stream>>>(erep, etype_W, etype_b, out);
    attn_kernel<<<256, 256, 0, stream>>>(erep, vrep, src_w, src_b, dst_w, dst_b, out);
}

// Round 7
// 496.823 us; speedup vs baseline: 5.5770x; 1.6899x over previous
//
#include <hip/hip_runtime.h>
#include <hip/hip_bf16.h>

// ---------------------------------------------------------------------------
// RNN_17214228922840: GraphRNN-ish model. fp32 I/O, bf16 MFMA compute.
//   B=128, TV=32, TE=64, VOCAB=1024, EMB=256, H=512 (3H=1536), REPR=128, NET=8
// Outputs (flat, fp32): O_vertex [128,1024,32] | O_edge [128,32,2,64] | O_edge_type [128,8,64]
// Row spaces are b-major: row = b*T + t.
// gi layout (step-major): [t][grp(8)][gate(3)][col(512)][r(16)]
// ---------------------------------------------------------------------------

typedef __bf16 bf16_t;
typedef bf16_t bf16x8 __attribute__((ext_vector_type(8)));
typedef bf16_t bf16x4 __attribute__((ext_vector_type(4)));
typedef float  f32x4  __attribute__((ext_vector_type(4)));

// workspace layout (bf16 element offsets)
#define OFF_GIV  0ull                    // 32*8*3*512*16 = 6291456
#define OFF_GIE  6291456ull              // 64*8*3*512*16 = 12582912
#define OFF_HV   18874368ull             // 128*32*512 (b-major)
#define OFF_HE   20971520ull             // 128*64*512 (b-major)
#define OFF_VREP 25165824ull             // 128*32*128
#define OFF_EREP 25690112ull             // 128*64*128
#define OFF_HBUF 26738688ull             // 16 slots * 2 parity * 8192
#define FLAG_BYTE_OFF 54001664ull        // 16 slots * 4 ints (poison 0xAA < 0 = self-reset)
#define OFF_CVT  27002880ull             // converted bf16 weights below
#define CVT_VEMB  0ull
#define CVT_EEMB  262144ull
#define CVT_VWI   270336ull
#define CVT_EWI   663552ull
#define CVT_VWH   1449984ull
#define CVT_EWH   2236416ull
#define CVT_VOUT  3022848ull
#define CVT_VREPW 3547136ull
#define CVT_EREPW 3612672ull

// output flat offsets (fp32 elements)
#define OUT_OV 0ull
#define OUT_OE 4194304ull
#define OUT_OT 4718592ull

__device__ __forceinline__ float fsigmoid(float x) {
    float e = __builtin_amdgcn_exp2f(-x * 1.4426950408889634f);
    return __builtin_amdgcn_rcpf(1.0f + e);
}
__device__ __forceinline__ float ftanh(float x) {
    x = fminf(x, 15.0f);
    float e = __builtin_amdgcn_exp2f(x * 2.8853900817779268f); // exp(2x)
    return (e - 1.0f) * __builtin_amdgcn_rcpf(e + 1.0f);
}

// ---------------------------------------------------------------------------
// prep: fp32 -> bf16 downcast of weights/embeddings (3592 blocks x 1024 elem)
// ---------------------------------------------------------------------------
__global__ __launch_bounds__(256) void prep_kernel(
    const float* __restrict__ vemb, const float* __restrict__ eemb,
    const float* __restrict__ vwi,  const float* __restrict__ ewi,
    const float* __restrict__ vwh,  const float* __restrict__ ewh,
    const float* __restrict__ voutw, const float* __restrict__ vrepw,
    const float* __restrict__ erepw, bf16_t* __restrict__ cvt)
{
    int blk = blockIdx.x;
    const float* src; bf16_t* dst; int lb;
    if (blk < 256)       { src = vemb;  dst = cvt + CVT_VEMB;  lb = blk; }
    else if (blk < 264)  { src = eemb;  dst = cvt + CVT_EEMB;  lb = blk - 256; }
    else if (blk < 648)  { src = vwi;   dst = cvt + CVT_VWI;   lb = blk - 264; }
    else if (blk < 1416) { src = ewi;   dst = cvt + CVT_EWI;   lb = blk - 648; }
    else if (blk < 2184) { src = vwh;   dst = cvt + CVT_VWH;   lb = blk - 1416; }
    else if (blk < 2952) { src = ewh;   dst = cvt + CVT_EWH;   lb = blk - 2184; }
    else if (blk < 3464) { src = voutw; dst = cvt + CVT_VOUT;  lb = blk - 2952; }
    else if (blk < 3528) { src = vrepw; dst = cvt + CVT_VREPW; lb = blk - 3464; }
    else                 { src = erepw; dst = cvt + CVT_EREPW; lb = blk - 3528; }
    int idx = lb * 1024 + threadIdx.x * 4;
    float4 v = *(const float4*)(src + idx);
    bf16x4 o;
    o[0] = (bf16_t)v.x; o[1] = (bf16_t)v.y; o[2] = (bf16_t)v.z; o[3] = (bf16_t)v.w;
    *(bf16x4*)(dst + idx) = o;
}

// ---------------------------------------------------------------------------
// Generic C = gather(A) @ W^T + bias GEMM. Wave computes 64x64 (4x4 MFMA tiles).
// Rows are b-major: row = b*TT + t.
// GATHER: 0 dense A[M,K]; 1 vertex emb gather (K=256); 2 edge emb pair (K=512)
// OUTMODE: 0 row-major C[row*N+col]
//          1 O_vertex: float4 at [(b*1024+col)*32 + t]
//          2 gi scatter (step-major): scalar at [((t*8+grp)*3+gate)*512+cw]*16 + r
// ---------------------------------------------------------------------------
template<int GATHER, int OUTMODE, int K, int TT, typename CT>
__global__ __launch_bounds__(256) void gemm_bt(
    const bf16_t* __restrict__ A, const bf16_t* __restrict__ W,
    const float* __restrict__ bias, CT* __restrict__ C,
    const int* __restrict__ gidx, const bf16_t* __restrict__ emb, int N)
{
    constexpr int K32 = K / 32;
    const int tid = threadIdx.x, lane = tid & 63, wv = tid >> 6;
    const int r16 = lane & 15, quad = lane >> 4, koff = quad * 8;
    const int mbase = blockIdx.x * 256 + wv * 64;
    const int nbase = blockIdx.y * 64;

    const bf16_t* ap0[4];
    const bf16_t* ap1[4];
#pragma unroll
    for (int i = 0; i < 4; ++i) {
        int row = mbase + i * 16 + r16;
        if (GATHER == 0) {
            ap0[i] = A + (size_t)row * K + koff;
            ap1[i] = ap0[i];
        } else if (GATHER == 1) {
            int idx = gidx[row];                    // row = b*32+t
            ap0[i] = emb + (size_t)idx * 256 + koff;
            ap1[i] = ap0[i];
        } else {
            int c = row * 3;                        // row = b*64+t
            ap0[i] = emb + (size_t)gidx[c] * 256 + koff;
            ap1[i] = emb + (size_t)gidx[c + 1] * 256 + koff;
        }
    }
    const bf16_t* bp[4];
#pragma unroll
    for (int j = 0; j < 4; ++j)
        bp[j] = W + (size_t)(nbase + j * 16 + r16) * K + koff;

    f32x4 acc[4][4];
#pragma unroll
    for (int i = 0; i < 4; ++i)
#pragma unroll
        for (int j = 0; j < 4; ++j) acc[i][j] = (f32x4){0.f, 0.f, 0.f, 0.f};

    for (int kc = 0; kc < K32; ++kc) {
        bf16x8 a[4], b[4];
#pragma unroll
        for (int i = 0; i < 4; ++i) {
            const bf16_t* p;
            if (GATHER == 2) p = (kc < 8) ? (ap0[i] + kc * 32) : (ap1[i] + (kc - 8) * 32);
            else             p = ap0[i] + kc * 32;
            a[i] = *(const bf16x8*)p;
        }
#pragma unroll
        for (int j = 0; j < 4; ++j) b[j] = *(const bf16x8*)(bp[j] + kc * 32);
#pragma unroll
        for (int i = 0; i < 4; ++i)
#pragma unroll
            for (int j = 0; j < 4; ++j)
                acc[i][j] = __builtin_amdgcn_mfma_f32_16x16x32_bf16(a[i], b[j], acc[i][j], 0, 0, 0);
    }

#pragma unroll
    for (int j = 0; j < 4; ++j) {
        int col = nbase + j * 16 + r16;
        float bf = bias[col];
        int gate = col >> 9, cw = col & 511;        // OUTMODE 2 decomposition
#pragma unroll
        for (int i = 0; i < 4; ++i) {
            int rowq = mbase + i * 16 + quad * 4;   // 4 consecutive t in one b
            if (OUTMODE == 1) {
                int b = rowq >> 5, t0 = rowq & 31;
                float4 v4;
                v4.x = acc[i][j][0] + bf; v4.y = acc[i][j][1] + bf;
                v4.z = acc[i][j][2] + bf; v4.w = acc[i][j][3] + bf;
                *(float4*)((float*)C + ((size_t)(b * 1024) + col) * 32 + t0) = v4;
            } else if (OUTMODE == 2) {
                int b = rowq / TT, t0 = rowq & (TT - 1);
                int grp = b >> 4, r = b & 15;
#pragma unroll
                for (int q = 0; q < 4; ++q)
                    C[(size_t)((((t0 + q) * 8 + grp) * 3 + gate) * 512 + cw) * 16 + r] =
                        (CT)(acc[i][j][q] + bf);
            } else {
#pragma unroll
                for (int q = 0; q < 4; ++q) {
                    int row = rowq + q;
                    C[(size_t)row * N + col] = (CT)(acc[i][j][q] + bf);
                }
            }
        }
    }
}

// ---------------------------------------------------------------------------
// Fused GRU scans (vertex blocks 0..31, edge blocks 32..63).
// Block = 512 thr (8 waves). Group = 16 batch rows, 4 blocks (128 h-cols each;
// Wh slice register-resident: 192 regs/lane on unified VGPR/AGPR file).
// Exchange: own slice written straight to next-parity LDS; remote 3 slices via
// MALL (agent scope). Release = h stores -> s_waitcnt(0) -> __syncthreads ->
// tid0 stores per-BLOCK flag. Acquire = per-wave poll of the 4 block flags
// (one 16B segment per spin iteration). gi is step-major so each step's gate
// inputs are 3 coalesced 512B regions per wave, streamed from HBM exactly once
// (R5/R6's t-fast gi layout caused 530MB of L2-miss refetch: 2B used per 64B
// line per step).
// ---------------------------------------------------------------------------
__global__ __launch_bounds__(512) void gru_scan(
    const bf16_t* __restrict__ giV, const bf16_t* __restrict__ giE,
    const bf16_t* __restrict__ WhV, const bf16_t* __restrict__ WhE,
    const float* __restrict__ bhV, const float* __restrict__ bhE,
    bf16_t* __restrict__ hV, bf16_t* __restrict__ hE,
    bf16_t* __restrict__ hbuf, int* __restrict__ flags)
{
    const int blk  = blockIdx.x;
    const int role = blk >> 5;          // 0 vertex, 1 edge
    const int lb   = blk & 31;
    const int g    = lb & 7;            // batch group; group's blocks == g (mod 8)
    const int s    = lb >> 3;           // col-slice 0..3
    const bf16_t* gi = role ? giE : giV;
    const bf16_t* Wh = role ? WhE : WhV;
    const float*  bh = role ? bhE : bhV;
    bf16_t* hout = role ? hE : hV;
    const int T = role ? 64 : 32;
    const int slot = role * 8 + g;
    bf16_t* buf0 = hbuf + (size_t)slot * 2 * 8192;
    int* fl = flags + slot * 4;
    const int bb = g * 16;

    const int tid = threadIdx.x, lane = tid & 63, wv = tid >> 6;
    const int r16 = lane & 15, quad = lane >> 4, koff = quad * 8;
    const int j = s * 128 + wv * 16 + r16;   // this lane's h column (0..511)
    const int rs0 = (s + 1) & 3, rs1 = (s + 2) & 3, rs2 = (s + 3) & 3;

    // --- Wh slice in registers: wfrag[gate][kc] (192 regs) ---
    bf16x8 wfrag[3][16];
#pragma unroll
    for (int gate = 0; gate < 3; ++gate) {
        const bf16_t* wrow = Wh + ((size_t)(gate * 512 + j)) * 512 + koff;
#pragma unroll
        for (int kc = 0; kc < 16; ++kc)
            wfrag[gate][kc] = *(const bf16x8*)(wrow + kc * 32);
    }
    const float bhr = bh[j], bhz = bh[512 + j], bhn = bh[1024 + j];
    float hq[4] = {0.f, 0.f, 0.f, 0.f};

    __shared__ __align__(16) bf16_t hbf[2][16][520];
    for (int i = tid; i < 16 * 512; i += 512)
        hbf[0][i >> 9][i & 511] = (bf16_t)0.f;   // h(0)=0; ordered by first barrier

    const int arow = tid >> 5, au = tid & 31;    // phase-A unit: row 0..15, 8B unit 0..31

    for (int t = 0; t < T; ++t) {
        // gi prefetch (step-major): 3 x 8B coalesced loads, issued before the poll
        bf16x4 gp[3];
        size_t gib = (size_t)((t * 8 + g) * 3) * 8192;    // *512*16
#pragma unroll
        for (int gg = 0; gg < 3; ++gg)
            gp[gg] = *(const bf16x4*)(gi + gib + (size_t)(gg * 512 + j) * 16 + quad * 4);

        if (t > 0) {
            // acquire: poll the 4 per-block flags (one 16B segment per iter)
            while (!__all((int)(__hip_atomic_load(&fl[lane & 3], __ATOMIC_RELAXED,
                                                  __HIP_MEMORY_SCOPE_AGENT) >= t))) { }
            asm volatile("" ::: "memory");
            // remote 3 slices of h(t) -> LDS parity t&1 (own slice already there)
            unsigned long long* src = (unsigned long long*)(buf0 + (size_t)(t & 1) * 8192);
            unsigned long long vv[3];
            vv[0] = __hip_atomic_load(src + arow * 128 + rs0 * 32 + au, __ATOMIC_RELAXED, __HIP_MEMORY_SCOPE_AGENT);
            vv[1] = __hip_atomic_load(src + arow * 128 + rs1 * 32 + au, __ATOMIC_RELAXED, __HIP_MEMORY_SCOPE_AGENT);
            vv[2] = __hip_atomic_load(src + arow * 128 + rs2 * 32 + au, __ATOMIC_RELAXED, __HIP_MEMORY_SCOPE_AGENT);
            *(unsigned long long*)&hbf[t & 1][arow][rs0 * 128 + au * 4] = vv[0];
            *(unsigned long long*)&hbf[t & 1][arow][rs1 * 128 + au * 4] = vv[1];
            *(unsigned long long*)&hbf[t & 1][arow][rs2 * 128 + au * 4] = vv[2];
        }
        __syncthreads();

        // MFMA: gh for this lane's 16-col strip, 3 gates
        const bf16_t (*cur)[520] = hbf[t & 1];
        f32x4 ar = {0.f,0.f,0.f,0.f}, az = {0.f,0.f,0.f,0.f}, an = {0.f,0.f,0.f,0.f};
#pragma unroll
        for (int kc = 0; kc < 16; ++kc) {
            bf16x8 a = *(const bf16x8*)&cur[r16][kc * 32 + koff];
            ar = __builtin_amdgcn_mfma_f32_16x16x32_bf16(a, wfrag[0][kc], ar, 0, 0, 0);
            az = __builtin_amdgcn_mfma_f32_16x16x32_bf16(a, wfrag[1][kc], az, 0, 0, 0);
            an = __builtin_amdgcn_mfma_f32_16x16x32_bf16(a, wfrag[2][kc], an, 0, 0, 0);
        }

        // gates + h update (C-frag: col=lane&15, row=quad*4+q)
        bf16_t hb4[4];
#pragma unroll
        for (int q = 0; q < 4; ++q) {
            float r = fsigmoid((float)gp[0][q] + ar[q] + bhr);
            float z = fsigmoid((float)gp[1][q] + az[q] + bhz);
            float n = ftanh((float)gp[2][q] + r * (an[q] + bhn));
            float hnew = (1.0f - z) * n + z * hq[q];
            hq[q] = hnew;
            hb4[q] = (bf16_t)hnew;
        }

        // own slice of h(t+1) -> next-parity LDS (never round-trips MALL)
        bf16_t (*nxt)[520] = hbf[(t + 1) & 1];
#pragma unroll
        for (int q = 0; q < 4; ++q) nxt[quad * 4 + q][j] = hb4[q];

        if (t + 1 < T) {
            // release: h(t+1) remote-visible via MALL, drain, barrier, flag
            bf16_t* dstg = buf0 + (size_t)((t + 1) & 1) * 8192;
#pragma unroll
            for (int q = 0; q < 4; ++q)
                __hip_atomic_store((unsigned short*)(dstg + (quad * 4 + q) * 512 + j),
                                   __builtin_bit_cast(unsigned short, hb4[q]),
                                   __ATOMIC_RELAXED, __HIP_MEMORY_SCOPE_AGENT);
            __builtin_amdgcn_s_waitcnt(0);
            __syncthreads();
            if (tid == 0)
                __hip_atomic_store(&fl[s], t + 1,
                                   __ATOMIC_RELAXED, __HIP_MEMORY_SCOPE_AGENT);
        } else {
            __syncthreads();
        }
        // hout (HBM) after the flag: latency overlaps the next poll
#pragma unroll
        for (int q = 0; q < 4; ++q)
            hout[((size_t)((bb + quad * 4 + q) * T + t)) * 512 + j] = hb4[q];
    }
}

// O_edge_type[b,k,te] = erep[b,te,:] . etype_W[k,:] + etype_b[k]
__global__ __launch_bounds__(256) void etype_kernel(
    const bf16_t* __restrict__ erep, const float* __restrict__ W,
    const float* __restrict__ bias, float* __restrict__ out)
{
    int o = blockIdx.x * 256 + threadIdx.x;      // 65536 outputs
    int te = o & 63, k = (o >> 6) & 7, b = o >> 9;
    float sacc = bias[k];
    const bf16_t* e = erep + ((size_t)(b * 64 + te)) * 128;
    const float* w = W + k * 128;
#pragma unroll 8
    for (int r = 0; r < 128; ++r) sacc += (float)e[r] * w[r];
    out[OUT_OT + o] = sacc;
}

// O_edge[b,tv,{0,1},te] = sum_r tanh(e[b,te,r]+v[b,tv,r]) * {src,dst}_w[r] + b
__global__ __launch_bounds__(256) void attn_kernel(
    const bf16_t* __restrict__ erep, const bf16_t* __restrict__ vrep,
    const float* __restrict__ src_w, const float* __restrict__ src_b,
    const float* __restrict__ dst_w, const float* __restrict__ dst_b,
    float* __restrict__ out)
{
    int b = blockIdx.x >> 1, half = blockIdx.x & 1;
    __shared__ float es[32][129], vs[32][129], swf[128], dwf[128];
    int tid = threadIdx.x;
    for (int f = tid; f < 32 * 128; f += 256) {
        int i = f >> 7, r = f & 127;
        es[i][r] = (float)erep[((size_t)(b * 64 + half * 32 + i)) * 128 + r];
        vs[i][r] = (float)vrep[((size_t)(b * 32 + i)) * 128 + r];
    }
    if (tid < 128) { swf[tid] = src_w[tid]; dwf[tid] = dst_w[tid]; }
    __syncthreads();
    float sb = src_b[0], db = dst_b[0];
    for (int p = tid; p < 1024; p += 256) {
        int te = p & 31, tv = p >> 5;
        float sacc = 0.f, dacc = 0.f;
#pragma unroll 4
        for (int r = 0; r < 128; ++r) {
            float u = ftanh(es[te][r] + vs[tv][r]);
            sacc += u * swf[r];
            dacc += u * dwf[r];
        }
        int teg = half * 32 + te;
        size_t base = OUT_OE + ((size_t)(b * 32 + tv) * 2) * 64;
        out[base + teg]      = sacc + sb;
        out[base + 64 + teg] = dacc + db;
    }
}

extern "C" void kernel_launch(void* const* d_in, const int* in_sizes, int n_in,
                              void* d_out, int out_size, void* d_ws, size_t ws_size,
                              hipStream_t stream)
{
    const int*   input_vertex = (const int*)d_in[0];
    const int*   input_edge   = (const int*)d_in[1];
    const float* vertex_emb   = (const float*)d_in[2];
    const float* v_Wi  = (const float*)d_in[3];
    const float* v_Wh  = (const float*)d_in[4];
    const float* v_bi  = (const float*)d_in[5];
    const float* v_bh  = (const float*)d_in[6];
    const float* vout_W = (const float*)d_in[7];
    const float* vout_b = (const float*)d_in[8];
    const float* vrep_W = (const float*)d_in[9];
    const float* vrep_b = (const float*)d_in[10];
    const float* edge_emb = (const float*)d_in[11];
    const float* e_Wi  = (const float*)d_in[12];
    const float* e_Wh  = (const float*)d_in[13];
    const float* e_bi  = (const float*)d_in[14];
    const float* e_bh  = (const float*)d_in[15];
    const float* erep_W = (const float*)d_in[16];
    const float* erep_b = (const float*)d_in[17];
    const float* etype_W = (const float*)d_in[18];
    const float* etype_b = (const float*)d_in[19];
    const float* src_w = (const float*)d_in[20];
    const float* src_b = (const float*)d_in[21];
    const float* dst_w = (const float*)d_in[22];
    const float* dst_b = (const float*)d_in[23];

    bf16_t* ws   = (bf16_t*)d_ws;
    bf16_t* giV  = ws + OFF_GIV;
    bf16_t* giE  = ws + OFF_GIE;
    bf16_t* hV   = ws + OFF_HV;
    bf16_t* hE   = ws + OFF_HE;
    bf16_t* vrep = ws + OFF_VREP;
    bf16_t* erep = ws + OFF_EREP;
    bf16_t* hbuf = ws + OFF_HBUF;
    bf16_t* cvt  = ws + OFF_CVT;
    int*    flags = (int*)((char*)d_ws + FLAG_BYTE_OFF);
    float*  out  = (float*)d_out;

    // downcast weights to bf16 (flags need no init: 0xAA poison is negative)
    prep_kernel<<<3592, 256, 0, stream>>>(vertex_emb, edge_emb, v_Wi, e_Wi, v_Wh, e_Wh,
                                          vout_W, vrep_W, erep_W, cvt);

    // gi projections -> step-major scatter layout
    gemm_bt<1, 2, 256, 32, bf16_t><<<dim3(16, 24), 256, 0, stream>>>(
        nullptr, cvt + CVT_VWI, v_bi, giV, input_vertex, cvt + CVT_VEMB, 1536);
    gemm_bt<2, 2, 512, 64, bf16_t><<<dim3(32, 24), 256, 0, stream>>>(
        nullptr, cvt + CVT_EWI, e_bi, giE, input_edge, cvt + CVT_EEMB, 1536);

    // fused vertex+edge GRU scans (4 blocks per group, per-block flag exchange)
    gru_scan<<<64, 512, 0, stream>>>(giV, giE, cvt + CVT_VWH, cvt + CVT_EWH,
                                     v_bh, e_bh, hV, hE, hbuf, flags);

    // output projections (rows b-major)
    gemm_bt<0, 1, 512, 32, float><<<dim3(16, 16), 256, 0, stream>>>(
        hV, cvt + CVT_VOUT, vout_b, out, nullptr, nullptr, 1024);
    gemm_bt<0, 0, 512, 32, bf16_t><<<dim3(16, 2), 256, 0, stream>>>(
        hV, cvt + CVT_VREPW, vrep_b, vrep, nullptr, nullptr, 128);
    gemm_bt<0, 0, 512, 64, bf16_t><<<dim3(32, 2), 256, 0, stream>>>(
        hE, cvt + CVT_EREPW, erep_b, erep, nullptr, nullptr, 128);

    etype_kernel<<<256, 256, 0, stream>>>(erep, etype_W, etype_b, out);
    attn_kernel<<<256, 256, 0, stream>>>(erep, vrep, src_w, src_b, dst_w, dst_b, out);
}

// Round 8
// 470.057 us; speedup vs baseline: 5.8946x; 1.0569x over previous
//
#include <hip/hip_runtime.h>
#include <hip/hip_bf16.h>

// ---------------------------------------------------------------------------
// RNN_17214228922840: GraphRNN-ish model. fp32 I/O, bf16 MFMA compute.
//   B=128, TV=32, TE=64, VOCAB=1024, EMB=256, H=512 (3H=1536), REPR=128, NET=8
// Outputs (flat, fp32): O_vertex [128,1024,32] | O_edge [128,32,2,64] | O_edge_type [128,8,64]
// Row spaces are b-major: row = b*T + t.
// gi layout: plain row-major [row = b*T + t][1536]  (full-line coalesced GEMM
// writes; R7's scatter layout caused ~1.6GB of cross-XCD partial-line RMW).
// ---------------------------------------------------------------------------

typedef __bf16 bf16_t;
typedef bf16_t bf16x8 __attribute__((ext_vector_type(8)));
typedef bf16_t bf16x4 __attribute__((ext_vector_type(4)));
typedef float  f32x4  __attribute__((ext_vector_type(4)));

// workspace layout (bf16 element offsets)
#define OFF_GIV  0ull                    // 4096*1536 = 6291456
#define OFF_GIE  6291456ull              // 8192*1536 = 12582912
#define OFF_HV   18874368ull             // 128*32*512 (b-major)
#define OFF_HE   20971520ull             // 128*64*512 (b-major)
#define OFF_VREP 25165824ull             // 128*32*128
#define OFF_EREP 25690112ull             // 128*64*128
#define OFF_HBUF 26738688ull             // 16 slots * 2 parity * 8192
#define FLAG_BYTE_OFF 54001664ull        // 16 slots * 4 ints (poison 0xAA < 0 = self-reset)
#define OFF_CVT  27002880ull             // converted bf16 weights below
#define CVT_VEMB  0ull
#define CVT_EEMB  262144ull
#define CVT_VWI   270336ull
#define CVT_EWI   663552ull
#define CVT_VWH   1449984ull
#define CVT_EWH   2236416ull
#define CVT_VOUT  3022848ull
#define CVT_VREPW 3547136ull
#define CVT_EREPW 3612672ull

// output flat offsets (fp32 elements)
#define OUT_OV 0ull
#define OUT_OE 4194304ull
#define OUT_OT 4718592ull

__device__ __forceinline__ float fsigmoid(float x) {
    float e = __builtin_amdgcn_exp2f(-x * 1.4426950408889634f);
    return __builtin_amdgcn_rcpf(1.0f + e);
}
__device__ __forceinline__ float ftanh(float x) {
    x = fminf(x, 15.0f);
    float e = __builtin_amdgcn_exp2f(x * 2.8853900817779268f); // exp(2x)
    return (e - 1.0f) * __builtin_amdgcn_rcpf(e + 1.0f);
}

// ---------------------------------------------------------------------------
// prep: fp32 -> bf16 downcast of weights/embeddings (3592 blocks x 1024 elem)
// ---------------------------------------------------------------------------
__global__ __launch_bounds__(256) void prep_kernel(
    const float* __restrict__ vemb, const float* __restrict__ eemb,
    const float* __restrict__ vwi,  const float* __restrict__ ewi,
    const float* __restrict__ vwh,  const float* __restrict__ ewh,
    const float* __restrict__ voutw, const float* __restrict__ vrepw,
    const float* __restrict__ erepw, bf16_t* __restrict__ cvt)
{
    int blk = blockIdx.x;
    const float* src; bf16_t* dst; int lb;
    if (blk < 256)       { src = vemb;  dst = cvt + CVT_VEMB;  lb = blk; }
    else if (blk < 264)  { src = eemb;  dst = cvt + CVT_EEMB;  lb = blk - 256; }
    else if (blk < 648)  { src = vwi;   dst = cvt + CVT_VWI;   lb = blk - 264; }
    else if (blk < 1416) { src = ewi;   dst = cvt + CVT_EWI;   lb = blk - 648; }
    else if (blk < 2184) { src = vwh;   dst = cvt + CVT_VWH;   lb = blk - 1416; }
    else if (blk < 2952) { src = ewh;   dst = cvt + CVT_EWH;   lb = blk - 2184; }
    else if (blk < 3464) { src = voutw; dst = cvt + CVT_VOUT;  lb = blk - 2952; }
    else if (blk < 3528) { src = vrepw; dst = cvt + CVT_VREPW; lb = blk - 3464; }
    else                 { src = erepw; dst = cvt + CVT_EREPW; lb = blk - 3528; }
    int idx = lb * 1024 + threadIdx.x * 4;
    float4 v = *(const float4*)(src + idx);
    bf16x4 o;
    o[0] = (bf16_t)v.x; o[1] = (bf16_t)v.y; o[2] = (bf16_t)v.z; o[3] = (bf16_t)v.w;
    *(bf16x4*)(dst + idx) = o;
}

// ---------------------------------------------------------------------------
// Generic C = gather(A) @ W^T + bias GEMM. Wave computes 64x64 (4x4 MFMA tiles).
// Rows are b-major: row = b*TT + t.
// GATHER: 0 dense A[M,K]; 1 vertex emb gather (K=256); 2 edge emb pair (K=512)
// OUTMODE: 0 row-major C[row*N+col]
//          1 O_vertex: float4 at [(b*1024+col)*32 + t]
// ---------------------------------------------------------------------------
template<int GATHER, int OUTMODE, int K, int TT, typename CT>
__global__ __launch_bounds__(256) void gemm_bt(
    const bf16_t* __restrict__ A, const bf16_t* __restrict__ W,
    const float* __restrict__ bias, CT* __restrict__ C,
    const int* __restrict__ gidx, const bf16_t* __restrict__ emb, int N)
{
    constexpr int K32 = K / 32;
    const int tid = threadIdx.x, lane = tid & 63, wv = tid >> 6;
    const int r16 = lane & 15, quad = lane >> 4, koff = quad * 8;
    const int mbase = blockIdx.x * 256 + wv * 64;
    const int nbase = blockIdx.y * 64;

    const bf16_t* ap0[4];
    const bf16_t* ap1[4];
#pragma unroll
    for (int i = 0; i < 4; ++i) {
        int row = mbase + i * 16 + r16;
        if (GATHER == 0) {
            ap0[i] = A + (size_t)row * K + koff;
            ap1[i] = ap0[i];
        } else if (GATHER == 1) {
            int idx = gidx[row];                    // row = b*32+t
            ap0[i] = emb + (size_t)idx * 256 + koff;
            ap1[i] = ap0[i];
        } else {
            int c = row * 3;                        // row = b*64+t
            ap0[i] = emb + (size_t)gidx[c] * 256 + koff;
            ap1[i] = emb + (size_t)gidx[c + 1] * 256 + koff;
        }
    }
    const bf16_t* bp[4];
#pragma unroll
    for (int j = 0; j < 4; ++j)
        bp[j] = W + (size_t)(nbase + j * 16 + r16) * K + koff;

    f32x4 acc[4][4];
#pragma unroll
    for (int i = 0; i < 4; ++i)
#pragma unroll
        for (int j = 0; j < 4; ++j) acc[i][j] = (f32x4){0.f, 0.f, 0.f, 0.f};

    for (int kc = 0; kc < K32; ++kc) {
        bf16x8 a[4], b[4];
#pragma unroll
        for (int i = 0; i < 4; ++i) {
            const bf16_t* p;
            if (GATHER == 2) p = (kc < 8) ? (ap0[i] + kc * 32) : (ap1[i] + (kc - 8) * 32);
            else             p = ap0[i] + kc * 32;
            a[i] = *(const bf16x8*)p;
        }
#pragma unroll
        for (int j = 0; j < 4; ++j) b[j] = *(const bf16x8*)(bp[j] + kc * 32);
#pragma unroll
        for (int i = 0; i < 4; ++i)
#pragma unroll
            for (int j = 0; j < 4; ++j)
                acc[i][j] = __builtin_amdgcn_mfma_f32_16x16x32_bf16(a[i], b[j], acc[i][j], 0, 0, 0);
    }

#pragma unroll
    for (int j = 0; j < 4; ++j) {
        int col = nbase + j * 16 + r16;
        float bf = bias[col];
#pragma unroll
        for (int i = 0; i < 4; ++i) {
            int rowq = mbase + i * 16 + quad * 4;   // 4 consecutive t in one b
            if (OUTMODE == 1) {
                int b = rowq >> 5, t0 = rowq & 31;
                float4 v4;
                v4.x = acc[i][j][0] + bf; v4.y = acc[i][j][1] + bf;
                v4.z = acc[i][j][2] + bf; v4.w = acc[i][j][3] + bf;
                *(float4*)((float*)C + ((size_t)(b * 1024) + col) * 32 + t0) = v4;
            } else {
#pragma unroll
                for (int q = 0; q < 4; ++q) {
                    int row = rowq + q;
                    C[(size_t)row * N + col] = (CT)(acc[i][j][q] + bf);
                }
            }
        }
    }
}

// ---------------------------------------------------------------------------
// Fused GRU scans (vertex blocks 0..31, edge blocks 32..63).
// Block = 512 thr (8 waves). Group = 16 batch rows, 4 blocks (128 h-cols each;
// Wh slice register-resident: 192 regs/lane on unified VGPR/AGPR file).
// Exchange: own slice written straight to next-parity LDS; remote 3 slices via
// MALL (agent scope). Release = h stores -> s_waitcnt(0) -> __syncthreads ->
// tid0 stores per-BLOCK flag. Acquire = per-wave poll of the 4 block flags
// (one 16B segment per spin iteration). gi is row-major [b*T+t][1536]: lane's
// 12 gate inputs are scalar loads, 16 lanes = 32B contiguous; adjacent waves
// cover each 64B line in the same step -> gi streams from HBM once.
// ---------------------------------------------------------------------------
__global__ __launch_bounds__(512) void gru_scan(
    const bf16_t* __restrict__ giV, const bf16_t* __restrict__ giE,
    const bf16_t* __restrict__ WhV, const bf16_t* __restrict__ WhE,
    const float* __restrict__ bhV, const float* __restrict__ bhE,
    bf16_t* __restrict__ hV, bf16_t* __restrict__ hE,
    bf16_t* __restrict__ hbuf, int* __restrict__ flags)
{
    const int blk  = blockIdx.x;
    const int role = blk >> 5;          // 0 vertex, 1 edge
    const int lb   = blk & 31;
    const int g    = lb & 7;            // batch group; group's blocks == g (mod 8)
    const int s    = lb >> 3;           // col-slice 0..3
    const bf16_t* gi = role ? giE : giV;
    const bf16_t* Wh = role ? WhE : WhV;
    const float*  bh = role ? bhE : bhV;
    bf16_t* hout = role ? hE : hV;
    const int T = role ? 64 : 32;
    const int slot = role * 8 + g;
    bf16_t* buf0 = hbuf + (size_t)slot * 2 * 8192;
    int* fl = flags + slot * 4;
    const int bb = g * 16;

    const int tid = threadIdx.x, lane = tid & 63, wv = tid >> 6;
    const int r16 = lane & 15, quad = lane >> 4, koff = quad * 8;
    const int j = s * 128 + wv * 16 + r16;   // this lane's h column (0..511)
    const int rs0 = (s + 1) & 3, rs1 = (s + 2) & 3, rs2 = (s + 3) & 3;

    // --- Wh slice in registers: wfrag[gate][kc] (192 regs) ---
    bf16x8 wfrag[3][16];
#pragma unroll
    for (int gate = 0; gate < 3; ++gate) {
        const bf16_t* wrow = Wh + ((size_t)(gate * 512 + j)) * 512 + koff;
#pragma unroll
        for (int kc = 0; kc < 16; ++kc)
            wfrag[gate][kc] = *(const bf16x8*)(wrow + kc * 32);
    }
    const float bhr = bh[j], bhz = bh[512 + j], bhn = bh[1024 + j];
    float hq[4] = {0.f, 0.f, 0.f, 0.f};

    __shared__ __align__(16) bf16_t hbf[2][16][520];
    for (int i = tid; i < 16 * 512; i += 512)
        hbf[0][i >> 9][i & 511] = (bf16_t)0.f;   // h(0)=0; ordered by first barrier

    const int arow = tid >> 5, au = tid & 31;    // phase-A unit: row 0..15, 8B unit 0..31

    for (int t = 0; t < T; ++t) {
        // gi prefetch (row-major): 12 scalar loads, issued before the poll.
        // 16 consecutive lanes hit 32B contiguous; wv and wv^1 cover the line.
        float gv[3][4];
#pragma unroll
        for (int gg = 0; gg < 3; ++gg)
#pragma unroll
            for (int q = 0; q < 4; ++q)
                gv[gg][q] = (float)gi[((size_t)((bb + quad * 4 + q) * T + t)) * 1536
                                      + gg * 512 + j];

        if (t > 0) {
            // acquire: poll the 4 per-block flags (one 16B segment per iter)
            while (!__all((int)(__hip_atomic_load(&fl[lane & 3], __ATOMIC_RELAXED,
                                                  __HIP_MEMORY_SCOPE_AGENT) >= t))) { }
            asm volatile("" ::: "memory");
            // remote 3 slices of h(t) -> LDS parity t&1 (own slice already there)
            unsigned long long* src = (unsigned long long*)(buf0 + (size_t)(t & 1) * 8192);
            unsigned long long vv[3];
            vv[0] = __hip_atomic_load(src + arow * 128 + rs0 * 32 + au, __ATOMIC_RELAXED, __HIP_MEMORY_SCOPE_AGENT);
            vv[1] = __hip_atomic_load(src + arow * 128 + rs1 * 32 + au, __ATOMIC_RELAXED, __HIP_MEMORY_SCOPE_AGENT);
            vv[2] = __hip_atomic_load(src + arow * 128 + rs2 * 32 + au, __ATOMIC_RELAXED, __HIP_MEMORY_SCOPE_AGENT);
            *(unsigned long long*)&hbf[t & 1][arow][rs0 * 128 + au * 4] = vv[0];
            *(unsigned long long*)&hbf[t & 1][arow][rs1 * 128 + au * 4] = vv[1];
            *(unsigned long long*)&hbf[t & 1][arow][rs2 * 128 + au * 4] = vv[2];
        }
        __syncthreads();

        // MFMA: gh for this lane's 16-col strip, 3 gates
        const bf16_t (*cur)[520] = hbf[t & 1];
        f32x4 ar = {0.f,0.f,0.f,0.f}, az = {0.f,0.f,0.f,0.f}, an = {0.f,0.f,0.f,0.f};
#pragma unroll
        for (int kc = 0; kc < 16; ++kc) {
            bf16x8 a = *(const bf16x8*)&cur[r16][kc * 32 + koff];
            ar = __builtin_amdgcn_mfma_f32_16x16x32_bf16(a, wfrag[0][kc], ar, 0, 0, 0);
            az = __builtin_amdgcn_mfma_f32_16x16x32_bf16(a, wfrag[1][kc], az, 0, 0, 0);
            an = __builtin_amdgcn_mfma_f32_16x16x32_bf16(a, wfrag[2][kc], an, 0, 0, 0);
        }

        // gates + h update (C-frag: col=lane&15, row=quad*4+q)
        bf16_t hb4[4];
#pragma unroll
        for (int q = 0; q < 4; ++q) {
            float r = fsigmoid(gv[0][q] + ar[q] + bhr);
            float z = fsigmoid(gv[1][q] + az[q] + bhz);
            float n = ftanh(gv[2][q] + r * (an[q] + bhn));
            float hnew = (1.0f - z) * n + z * hq[q];
            hq[q] = hnew;
            hb4[q] = (bf16_t)hnew;
        }

        // own slice of h(t+1) -> next-parity LDS (never round-trips MALL)
        bf16_t (*nxt)[520] = hbf[(t + 1) & 1];
#pragma unroll
        for (int q = 0; q < 4; ++q) nxt[quad * 4 + q][j] = hb4[q];

        if (t + 1 < T) {
            // release: h(t+1) remote-visible via MALL, drain, barrier, flag
            bf16_t* dstg = buf0 + (size_t)((t + 1) & 1) * 8192;
#pragma unroll
            for (int q = 0; q < 4; ++q)
                __hip_atomic_store((unsigned short*)(dstg + (quad * 4 + q) * 512 + j),
                                   __builtin_bit_cast(unsigned short, hb4[q]),
                                   __ATOMIC_RELAXED, __HIP_MEMORY_SCOPE_AGENT);
            __builtin_amdgcn_s_waitcnt(0);
            __syncthreads();
            if (tid == 0)
                __hip_atomic_store(&fl[s], t + 1,
                                   __ATOMIC_RELAXED, __HIP_MEMORY_SCOPE_AGENT);
        } else {
            __syncthreads();
        }
        // hout (HBM) after the flag: latency overlaps the next poll
#pragma unroll
        for (int q = 0; q < 4; ++q)
            hout[((size_t)((bb + quad * 4 + q) * T + t)) * 512 + j] = hb4[q];
    }
}

// O_edge_type[b,k,te] = erep[b,te,:] . etype_W[k,:] + etype_b[k]
__global__ __launch_bounds__(256) void etype_kernel(
    const bf16_t* __restrict__ erep, const float* __restrict__ W,
    const float* __restrict__ bias, float* __restrict__ out)
{
    int o = blockIdx.x * 256 + threadIdx.x;      // 65536 outputs
    int te = o & 63, k = (o >> 6) & 7, b = o >> 9;
    float sacc = bias[k];
    const bf16_t* e = erep + ((size_t)(b * 64 + te)) * 128;
    const float* w = W + k * 128;
#pragma unroll 8
    for (int r = 0; r < 128; ++r) sacc += (float)e[r] * w[r];
    out[OUT_OT + o] = sacc;
}

// O_edge[b,tv,{0,1},te] = sum_r tanh(e[b,te,r]+v[b,tv,r]) * {src,dst}_w[r] + b
__global__ __launch_bounds__(256) void attn_kernel(
    const bf16_t* __restrict__ erep, const bf16_t* __restrict__ vrep,
    const float* __restrict__ src_w, const float* __restrict__ src_b,
    const float* __restrict__ dst_w, const float* __restrict__ dst_b,
    float* __restrict__ out)
{
    int b = blockIdx.x >> 1, half = blockIdx.x & 1;
    __shared__ float es[32][129], vs[32][129], swf[128], dwf[128];
    int tid = threadIdx.x;
    for (int f = tid; f < 32 * 128; f += 256) {
        int i = f >> 7, r = f & 127;
        es[i][r] = (float)erep[((size_t)(b * 64 + half * 32 + i)) * 128 + r];
        vs[i][r] = (float)vrep[((size_t)(b * 32 + i)) * 128 + r];
    }
    if (tid < 128) { swf[tid] = src_w[tid]; dwf[tid] = dst_w[tid]; }
    __syncthreads();
    float sb = src_b[0], db = dst_b[0];
    for (int p = tid; p < 1024; p += 256) {
        int te = p & 31, tv = p >> 5;
        float sacc = 0.f, dacc = 0.f;
#pragma unroll 4
        for (int r = 0; r < 128; ++r) {
            float u = ftanh(es[te][r] + vs[tv][r]);
            sacc += u * swf[r];
            dacc += u * dwf[r];
        }
        int teg = half * 32 + te;
        size_t base = OUT_OE + ((size_t)(b * 32 + tv) * 2) * 64;
        out[base + teg]      = sacc + sb;
        out[base + 64 + teg] = dacc + db;
    }
}

extern "C" void kernel_launch(void* const* d_in, const int* in_sizes, int n_in,
                              void* d_out, int out_size, void* d_ws, size_t ws_size,
                              hipStream_t stream)
{
    const int*   input_vertex = (const int*)d_in[0];
    const int*   input_edge   = (const int*)d_in[1];
    const float* vertex_emb   = (const float*)d_in[2];
    const float* v_Wi  = (const float*)d_in[3];
    const float* v_Wh  = (const float*)d_in[4];
    const float* v_bi  = (const float*)d_in[5];
    const float* v_bh  = (const float*)d_in[6];
    const float* vout_W = (const float*)d_in[7];
    const float* vout_b = (const float*)d_in[8];
    const float* vrep_W = (const float*)d_in[9];
    const float* vrep_b = (const float*)d_in[10];
    const float* edge_emb = (const float*)d_in[11];
    const float* e_Wi  = (const float*)d_in[12];
    const float* e_Wh  = (const float*)d_in[13];
    const float* e_bi  = (const float*)d_in[14];
    const float* e_bh  = (const float*)d_in[15];
    const float* erep_W = (const float*)d_in[16];
    const float* erep_b = (const float*)d_in[17];
    const float* etype_W = (const float*)d_in[18];
    const float* etype_b = (const float*)d_in[19];
    const float* src_w = (const float*)d_in[20];
    const float* src_b = (const float*)d_in[21];
    const float* dst_w = (const float*)d_in[22];
    const float* dst_b = (const float*)d_in[23];

    bf16_t* ws   = (bf16_t*)d_ws;
    bf16_t* giV  = ws + OFF_GIV;
    bf16_t* giE  = ws + OFF_GIE;
    bf16_t* hV   = ws + OFF_HV;
    bf16_t* hE   = ws + OFF_HE;
    bf16_t* vrep = ws + OFF_VREP;
    bf16_t* erep = ws + OFF_EREP;
    bf16_t* hbuf = ws + OFF_HBUF;
    bf16_t* cvt  = ws + OFF_CVT;
    int*    flags = (int*)((char*)d_ws + FLAG_BYTE_OFF);
    float*  out  = (float*)d_out;

    // downcast weights to bf16 (flags need no init: 0xAA poison is negative)
    prep_kernel<<<3592, 256, 0, stream>>>(vertex_emb, edge_emb, v_Wi, e_Wi, v_Wh, e_Wh,
                                          vout_W, vrep_W, erep_W, cvt);

    // gi projections -> row-major [b*T+t][1536]
    gemm_bt<1, 0, 256, 32, bf16_t><<<dim3(16, 24), 256, 0, stream>>>(
        nullptr, cvt + CVT_VWI, v_bi, giV, input_vertex, cvt + CVT_VEMB, 1536);
    gemm_bt<2, 0, 512, 64, bf16_t><<<dim3(32, 24), 256, 0, stream>>>(
        nullptr, cvt + CVT_EWI, e_bi, giE, input_edge, cvt + CVT_EEMB, 1536);

    // fused vertex+edge GRU scans (4 blocks per group, per-block flag exchange)
    gru_scan<<<64, 512, 0, stream>>>(giV, giE, cvt + CVT_VWH, cvt + CVT_EWH,
                                     v_bh, e_bh, hV, hE, hbuf, flags);

    // output projections (rows b-major)
    gemm_bt<0, 1, 512, 32, float><<<dim3(16, 16), 256, 0, stream>>>(
        hV, cvt + CVT_VOUT, vout_b, out, nullptr, nullptr, 1024);
    gemm_bt<0, 0, 512, 32, bf16_t><<<dim3(16, 2), 256, 0, stream>>>(
        hV, cvt + CVT_VREPW, vrep_b, vrep, nullptr, nullptr, 128);
    gemm_bt<0, 0, 512, 64, bf16_t><<<dim3(32, 2), 256, 0, stream>>>(
        hE, cvt + CVT_EREPW, erep_b, erep, nullptr, nullptr, 128);

    etype_kernel<<<256, 256, 0, stream>>>(erep, etype_W, etype_b, out);
    attn_kernel<<<256, 256, 0, stream>>>(erep, vrep, src_w, src_b, dst_w, dst_b, out);
}